// Round 2
// baseline (8104.029 us; speedup 1.0000x reference)
//
#include <hip/hip_runtime.h>
#include <math.h>

#define BATCHN 8
#define SEQ    2048
#define BS     (BATCHN*SEQ)      // 16384 rows
#define OBSD   256
#define DM     768
#define DI     1536
#define DST    16
#define DTR    48
#define NXP    80                // DTR + 2*DST

typedef unsigned short bf16_t;

__device__ __forceinline__ float bf2f(bf16_t b) {
    return __uint_as_float(((unsigned)b) << 16);
}
__device__ __forceinline__ bf16_t f2bf(float f) {
    unsigned u = __float_as_uint(f);
    unsigned r = (u + 0x7FFFu + ((u >> 16) & 1u)) >> 16;
    return (bf16_t)r;
}
__device__ __forceinline__ float fast_sigmoid(float x) {
    return __builtin_amdgcn_rcpf(1.0f + __expf(-x));
}

// ---------------- LayerNorm (one block per row), fp32 in, templated out ----------------
template<typename TOUT>
__global__ __launch_bounds__(256) void ln_kernel(
    const float* __restrict__ in, const float* __restrict__ g,
    const float* __restrict__ bta, TOUT* __restrict__ out, int D)
{
    int row = blockIdx.x;
    const float4* ip = (const float4*)(in + (size_t)row * D);
    const float4* gp = (const float4*)g;
    const float4* bp = (const float4*)bta;
    int nv = D >> 2;
    float sum = 0.f, sq = 0.f;
    for (int i = threadIdx.x; i < nv; i += 256) {
        float4 v = ip[i];
        sum += v.x + v.y + v.z + v.w;
        sq  += v.x*v.x + v.y*v.y + v.z*v.z + v.w*v.w;
    }
    for (int o = 32; o; o >>= 1) { sum += __shfl_down(sum, o); sq += __shfl_down(sq, o); }
    __shared__ float rs[4], rq[4];
    int lane = threadIdx.x & 63, wv = threadIdx.x >> 6;
    if (lane == 0) { rs[wv] = sum; rq[wv] = sq; }
    __syncthreads();
    sum = rs[0] + rs[1] + rs[2] + rs[3];
    sq  = rq[0] + rq[1] + rq[2] + rq[3];
    float inv  = 1.0f / (float)D;
    float mean = sum * inv;
    float var  = sq * inv - mean * mean;
    float rstd = rsqrtf(var + 1e-5f);
    for (int i = threadIdx.x; i < nv; i += 256) {
        float4 v = ip[i], gg = gp[i], bb = bp[i];
        float o0 = (v.x - mean) * rstd * gg.x + bb.x;
        float o1 = (v.y - mean) * rstd * gg.y + bb.y;
        float o2 = (v.z - mean) * rstd * gg.z + bb.z;
        float o3 = (v.w - mean) * rstd * gg.w + bb.w;
        if constexpr (sizeof(TOUT) == 4) {
            ((float4*)out)[(size_t)row * nv + i] = make_float4(o0, o1, o2, o3);
        } else {
            ushort4 p;
            p.x = f2bf(o0); p.y = f2bf(o1); p.z = f2bf(o2); p.w = f2bf(o3);
            ((ushort4*)out)[(size_t)row * nv + i] = p;
        }
    }
}

// ---------------- Tiled GEMM: C(M,N) = A(M,K) @ W(N,K)^T, fp32 accumulate ----------------
// TA: float or bf16_t (A storage). TC: float or bf16_t (C storage).
// EPI: 0 = bias(if any), 1 = softplus(after bias), 2 = accumulate into C (TC=float only)
template<typename TA, typename TC, int EPI>
__global__ __launch_bounds__(256) void gemm_kernel(
    const TA* __restrict__ A, int lda,
    const float* __restrict__ W, const float* __restrict__ bias,
    TC* __restrict__ C, int ldc, int N, int K)
{
    __shared__ float As[64][17];
    __shared__ float Ws[64][17];
    const int tid  = threadIdx.x;
    const int bm   = blockIdx.y * 64;
    const int bn   = blockIdx.x * 64;
    const int arow = tid >> 2;          // 0..63
    const int ac4  = (tid & 3) << 2;    // 0,4,8,12
    const int tx   = tid & 15;          // n
    const int ty   = tid >> 4;          // m
    float acc[4][4] = {};
    const TA* Aptr = A + (size_t)(bm + arow) * lda + ac4;
    const int wrow = bn + arow;
    const float* Wptr = W + (size_t)wrow * K + ac4;
    for (int k0 = 0; k0 < K; k0 += 16) {
        float a0, a1, a2, a3;
        if constexpr (sizeof(TA) == 2) {
            ushort4 av = *(const ushort4*)(Aptr + k0);
            a0 = bf2f(av.x); a1 = bf2f(av.y); a2 = bf2f(av.z); a3 = bf2f(av.w);
        } else {
            float4 av = *(const float4*)(Aptr + k0);
            a0 = av.x; a1 = av.y; a2 = av.z; a3 = av.w;
        }
        float4 wv = make_float4(0.f, 0.f, 0.f, 0.f);
        if (wrow < N) wv = *(const float4*)(Wptr + k0);
        As[arow][ac4+0] = a0;   As[arow][ac4+1] = a1;
        As[arow][ac4+2] = a2;   As[arow][ac4+3] = a3;
        Ws[arow][ac4+0] = wv.x; Ws[arow][ac4+1] = wv.y;
        Ws[arow][ac4+2] = wv.z; Ws[arow][ac4+3] = wv.w;
        __syncthreads();
        #pragma unroll
        for (int kk = 0; kk < 16; ++kk) {
            float a[4], b[4];
            #pragma unroll
            for (int i = 0; i < 4; ++i) a[i] = As[ty*4 + i][kk];
            #pragma unroll
            for (int j = 0; j < 4; ++j) b[j] = Ws[tx*4 + j][kk];
            #pragma unroll
            for (int i = 0; i < 4; ++i)
                #pragma unroll
                for (int j = 0; j < 4; ++j)
                    acc[i][j] += a[i] * b[j];
        }
        __syncthreads();
    }
    #pragma unroll
    for (int i = 0; i < 4; ++i) {
        int row = bm + ty*4 + i;
        #pragma unroll
        for (int j = 0; j < 4; ++j) {
            int col = bn + tx*4 + j;
            if (col < N) {
                float v = acc[i][j];
                if (bias) v += bias[col];
                if (EPI == 1) { float ax = fabsf(v); v = fmaxf(v, 0.f) + log1pf(__expf(-ax)); }
                size_t off = (size_t)row * ldc + col;
                if constexpr (sizeof(TC) == 2) {
                    C[off] = f2bf(v);
                } else {
                    if (EPI == 2) v += C[off];
                    C[off] = v;
                }
            }
        }
    }
}

// ---------------- Causal depthwise conv (D_CONV=4) + SiLU: RAW(bf16) -> U(bf16) ----------------
__global__ __launch_bounds__(256) void conv_silu_kernel(
    const bf16_t* __restrict__ raw, const float* __restrict__ cw,
    const float* __restrict__ cb, bf16_t* __restrict__ U)
{
    int idx = blockIdx.x * 256 + threadIdx.x;    // over BS*DI
    int d = idx % DI;
    int t = idx / DI;
    int s = t & (SEQ - 1);
    const bf16_t* base = raw + (size_t)t * DI + d;
    const float4 w = *(const float4*)(cw + d * 4);
    float acc = cb[d] + w.w * bf2f(base[0]);
    if (s >= 1) acc += w.z * bf2f(base[-DI]);
    if (s >= 2) acc += w.y * bf2f(base[-2*DI]);
    if (s >= 3) acc += w.x * bf2f(base[-3*DI]);
    U[(size_t)t * DI + d] = f2bf(acc * fast_sigmoid(acc));
}

// ---------------- Selective scan (+ D skip, * silu(z)); y written in-place over Z ----------------
__global__ __launch_bounds__(256) void scan_kernel(
    const bf16_t* __restrict__ U, const bf16_t* __restrict__ DT,
    const float* __restrict__ XDBL, const float* __restrict__ A_log,
    const float* __restrict__ Dp, bf16_t* __restrict__ Z)
{
    const int d = blockIdx.x * 256 + threadIdx.x;    // 0..DI-1
    const int b = blockIdx.y;
    float Arow[DST];
    #pragma unroll
    for (int n = 0; n < DST; ++n) Arow[n] = -__expf(A_log[(size_t)d * DST + n]);
    const float dp = Dp[d];
    float h[DST];
    #pragma unroll
    for (int n = 0; n < DST; ++n) h[n] = 0.f;
    __shared__ float bc[64][32];
    const size_t tbase = (size_t)b * SEQ;
    for (int c0 = 0; c0 < SEQ; c0 += 64) {
        __syncthreads();
        for (int q = threadIdx.x; q < 64 * 32; q += 256) {
            int tt = q >> 5, j = q & 31;
            bc[tt][j] = XDBL[(tbase + c0 + tt) * NXP + DTR + j];
        }
        __syncthreads();
        for (int tt = 0; tt < 64; ++tt) {
            size_t t = tbase + c0 + tt;
            float ut  = bf2f(U[t * DI + d]);
            float dtt = bf2f(DT[t * DI + d]);
            float du = dtt * ut;
            float y = 0.f;
            #pragma unroll
            for (int n = 0; n < DST; ++n) {
                float dA = __expf(dtt * Arow[n]);
                h[n] = h[n] * dA + du * bc[tt][n];
                y += h[n] * bc[tt][DST + n];
            }
            y += ut * dp;
            float z = bf2f(Z[t * DI + d]);
            Z[t * DI + d] = f2bf(y * z * fast_sigmoid(z));
        }
    }
}

extern "C" void kernel_launch(void* const* d_in, const int* in_sizes, int n_in,
                              void* d_out, int out_size, void* d_ws, size_t ws_size,
                              hipStream_t stream) {
    const float* obs       = (const float*)d_in[0];
    const float* in_norm_g = (const float*)d_in[1];
    const float* in_norm_b = (const float*)d_in[2];
    const float* in_W      = (const float*)d_in[3];
    const float* in_b      = (const float*)d_in[4];
    const float* norm_g    = (const float*)d_in[5];
    const float* norm_b    = (const float*)d_in[6];
    const float* inproj_W  = (const float*)d_in[7];
    const float* conv_W    = (const float*)d_in[8];
    const float* conv_b    = (const float*)d_in[9];
    const float* xproj_W   = (const float*)d_in[10];
    const float* dt_W      = (const float*)d_in[11];
    const float* dt_b      = (const float*)d_in[12];
    const float* A_log     = (const float*)d_in[13];
    const float* D_param   = (const float*)d_in[14];
    const float* outproj_W = (const float*)d_in[15];
    const float* out_W     = (const float*)d_in[16];
    const float* out_b     = (const float*)d_in[17];
    float* out = (float*)d_out;

    // Workspace layout (~207 MB total):
    //   X    : BS*DM  fp32 (residual, persistent)
    //   XDBL : BS*NXP fp32
    //   Z    : BS*DI  bf16 (z; scan writes gated y in-place) | aliases OBSN (fp32 BS*OBSD)
    //   U    : BS*DI  bf16 (u after conv+silu)               | aliases XN  (bf16 BS*DM)
    //   RAW  : BS*DI  bf16 (u_raw from inproj; then dt)
    float*  X    = (float*)d_ws;
    float*  XDBL = X + (size_t)BS * DM;
    bf16_t* Z    = (bf16_t*)(XDBL + (size_t)BS * NXP);
    bf16_t* U    = Z + (size_t)BS * DI;
    bf16_t* RAW  = U + (size_t)BS * DI;
    float*  OBSN = (float*)Z;   // live only before layer loop
    bf16_t* XN   = U;           // live only between ln and inproj

    // 1) input layernorm + in projection
    ln_kernel<float><<<BS, 256, 0, stream>>>(obs, in_norm_g, in_norm_b, OBSN, OBSD);
    gemm_kernel<float, float, 0><<<dim3(DM/64, BS/64), 256, 0, stream>>>(
        OBSN, OBSD, in_W, in_b, X, DM, DM, OBSD);

    for (int l = 0; l < 2; ++l) {
        const float* ipW = inproj_W  + (size_t)l * (2*DI) * DM;
        const float* cW  = conv_W    + (size_t)l * DI * 4;
        const float* cB  = conv_b    + (size_t)l * DI;
        const float* xpW = xproj_W   + (size_t)l * NXP * DI;
        const float* dW  = dt_W      + (size_t)l * DI * DTR;
        const float* dB  = dt_b      + (size_t)l * DI;
        const float* Al  = A_log     + (size_t)l * DI * DST;
        const float* Dpl = D_param   + (size_t)l * DI;
        const float* opW = outproj_W + (size_t)l * DM * DI;

        ln_kernel<bf16_t><<<BS, 256, 0, stream>>>(X, norm_g + l*DM, norm_b + l*DM, XN, DM);
        // u_raw = xn @ ipW[:DI].T
        gemm_kernel<bf16_t, bf16_t, 0><<<dim3(DI/64, BS/64), 256, 0, stream>>>(
            XN, DM, ipW, nullptr, RAW, DI, DI, DM);
        // z = xn @ ipW[DI:].T
        gemm_kernel<bf16_t, bf16_t, 0><<<dim3(DI/64, BS/64), 256, 0, stream>>>(
            XN, DM, ipW + (size_t)DI * DM, nullptr, Z, DI, DI, DM);
        // u = silu(conv(u_raw))
        conv_silu_kernel<<<(BS*DI)/256, 256, 0, stream>>>(RAW, cW, cB, U);
        // x_dbl = u @ xpW.T  (N = 80)
        gemm_kernel<bf16_t, float, 0><<<dim3((NXP+63)/64, BS/64), 256, 0, stream>>>(
            U, DI, xpW, nullptr, XDBL, NXP, NXP, DI);
        // dt = softplus(x_dbl[:, :48] @ dtW.T + dt_b) -> RAW (u_raw dead)
        gemm_kernel<float, bf16_t, 1><<<dim3(DI/64, BS/64), 256, 0, stream>>>(
            XDBL, NXP, dW, dB, RAW, DI, DI, DTR);
        // selective scan + D skip + *silu(z); result in-place into Z
        scan_kernel<<<dim3(DI/256, BATCHN), 256, 0, stream>>>(
            U, RAW, XDBL, Al, Dpl, Z);
        // x += y @ opW.T
        gemm_kernel<bf16_t, float, 2><<<dim3(DM/64, BS/64), 256, 0, stream>>>(
            Z, DI, opW, nullptr, X, DM, DM, DI);
    }

    // out = x @ out_W.T + out_b  (N = 64)
    gemm_kernel<float, float, 0><<<dim3(1, BS/64), 256, 0, stream>>>(
        X, DM, out_W, out_b, out, 64, 64, DM);
}

// Round 3
// 4332.719 us; speedup vs baseline: 1.8704x; 1.8704x over previous
//
#include <hip/hip_runtime.h>
#include <math.h>

#define BATCHN 8
#define SEQ    2048
#define BS     (BATCHN*SEQ)      // 16384 rows
#define OBSD   256
#define DM     768
#define DI     1536
#define DST    16
#define DTR    48
#define NXP    80                // DTR + 2*DST

typedef unsigned short bf16_t;
typedef __attribute__((ext_vector_type(8))) short bf16x8;
typedef __attribute__((ext_vector_type(4))) float f32x4;

__device__ __forceinline__ float bf2f(bf16_t b) {
    return __uint_as_float(((unsigned)b) << 16);
}
__device__ __forceinline__ bf16_t f2bf(float f) {
    unsigned u = __float_as_uint(f);
    unsigned r = (u + 0x7FFFu + ((u >> 16) & 1u)) >> 16;
    return (bf16_t)r;
}
__device__ __forceinline__ float fast_sigmoid(float x) {
    return __builtin_amdgcn_rcpf(1.0f + __expf(-x));
}

// ---------------- fp32 -> bf16 weight conversion ----------------
__global__ __launch_bounds__(256) void cvt_f2bf_kernel(
    const float* __restrict__ in, bf16_t* __restrict__ out, int n4)
{
    int i = blockIdx.x * 256 + threadIdx.x;
    if (i >= n4) return;
    float4 v = ((const float4*)in)[i];
    ushort4 p;
    p.x = f2bf(v.x); p.y = f2bf(v.y); p.z = f2bf(v.z); p.w = f2bf(v.w);
    ((ushort4*)out)[i] = p;
}

// ---------------- LayerNorm (one block per row), fp32 in, templated out ----------------
template<typename TOUT>
__global__ __launch_bounds__(256) void ln_kernel(
    const float* __restrict__ in, const float* __restrict__ g,
    const float* __restrict__ bta, TOUT* __restrict__ out, int D)
{
    int row = blockIdx.x;
    const float4* ip = (const float4*)(in + (size_t)row * D);
    const float4* gp = (const float4*)g;
    const float4* bp = (const float4*)bta;
    int nv = D >> 2;
    float sum = 0.f, sq = 0.f;
    for (int i = threadIdx.x; i < nv; i += 256) {
        float4 v = ip[i];
        sum += v.x + v.y + v.z + v.w;
        sq  += v.x*v.x + v.y*v.y + v.z*v.z + v.w*v.w;
    }
    for (int o = 32; o; o >>= 1) { sum += __shfl_down(sum, o); sq += __shfl_down(sq, o); }
    __shared__ float rs[4], rq[4];
    int lane = threadIdx.x & 63, wv = threadIdx.x >> 6;
    if (lane == 0) { rs[wv] = sum; rq[wv] = sq; }
    __syncthreads();
    sum = rs[0] + rs[1] + rs[2] + rs[3];
    sq  = rq[0] + rq[1] + rq[2] + rq[3];
    float inv  = 1.0f / (float)D;
    float mean = sum * inv;
    float var  = sq * inv - mean * mean;
    float rstd = rsqrtf(var + 1e-5f);
    for (int i = threadIdx.x; i < nv; i += 256) {
        float4 v = ip[i], gg = gp[i], bb = bp[i];
        float o0 = (v.x - mean) * rstd * gg.x + bb.x;
        float o1 = (v.y - mean) * rstd * gg.y + bb.y;
        float o2 = (v.z - mean) * rstd * gg.z + bb.z;
        float o3 = (v.w - mean) * rstd * gg.w + bb.w;
        if constexpr (sizeof(TOUT) == 4) {
            ((float4*)out)[(size_t)row * nv + i] = make_float4(o0, o1, o2, o3);
        } else {
            ushort4 p;
            p.x = f2bf(o0); p.y = f2bf(o1); p.z = f2bf(o2); p.w = f2bf(o3);
            ((ushort4*)out)[(size_t)row * nv + i] = p;
        }
    }
}

// ---------------- MFMA bf16 GEMM: C(M,N) = A(M,K) @ W(N,K)^T ----------------
// Block 256 thr = 4 waves (2x2), wave tile 64x64, block tile 128x128.
// Requires M%128==0, N%128==0, K%32==0. A,W row-major bf16 with stride = K.
// EPI: 0 = (+bias) store; 2 = accumulate into fp32 C.
template<typename TC, int EPI>
__global__ __launch_bounds__(256, 2) void gemm_mfma_kernel(
    const bf16_t* __restrict__ A, int lda,
    const bf16_t* __restrict__ W, int ldw,
    const float* __restrict__ bias,
    TC* __restrict__ C, int ldc, int K)
{
    const int tid  = threadIdx.x;
    const int wid  = tid >> 6;
    const int lane = tid & 63;
    const int wr   = wid >> 1, wc = wid & 1;
    const int bm   = blockIdx.y * 128 + wr * 64;
    const int bn   = blockIdx.x * 128 + wc * 64;
    const int l15  = lane & 15;
    const int kq   = lane >> 4;          // 0..3

    f32x4 acc[4][4];
    #pragma unroll
    for (int i = 0; i < 4; ++i)
        #pragma unroll
        for (int j = 0; j < 4; ++j)
            acc[i][j] = (f32x4){0.f, 0.f, 0.f, 0.f};

    const bf16_t* Ap = A + (size_t)(bm + l15) * lda + kq * 8;
    const bf16_t* Wp = W + (size_t)(bn + l15) * ldw + kq * 8;

    for (int k0 = 0; k0 < K; k0 += 32) {
        bf16x8 af[4], bf[4];
        #pragma unroll
        for (int i = 0; i < 4; ++i)
            af[i] = *(const bf16x8*)(Ap + (size_t)i * 16 * lda + k0);
        #pragma unroll
        for (int j = 0; j < 4; ++j)
            bf[j] = *(const bf16x8*)(Wp + (size_t)j * 16 * ldw + k0);
        #pragma unroll
        for (int i = 0; i < 4; ++i)
            #pragma unroll
            for (int j = 0; j < 4; ++j)
                acc[i][j] = __builtin_amdgcn_mfma_f32_16x16x32_bf16(
                    af[i], bf[j], acc[i][j], 0, 0, 0);
    }

    #pragma unroll
    for (int i = 0; i < 4; ++i) {
        int r0 = bm + i * 16 + kq * 4;
        #pragma unroll
        for (int j = 0; j < 4; ++j) {
            int col = bn + j * 16 + l15;
            float bb = bias ? bias[col] : 0.0f;
            #pragma unroll
            for (int r = 0; r < 4; ++r) {
                size_t off = (size_t)(r0 + r) * ldc + col;
                float v = acc[i][j][r] + bb;
                if constexpr (sizeof(TC) == 2) {
                    C[off] = f2bf(v);
                } else {
                    if (EPI == 2) v += C[off];
                    C[off] = v;
                }
            }
        }
    }
}

// ---------------- Scalar fp32-accum GEMM (small/odd shapes) ----------------
template<typename TA, typename TC, int EPI>
__global__ __launch_bounds__(256) void gemm_kernel(
    const TA* __restrict__ A, int lda,
    const float* __restrict__ W, const float* __restrict__ bias,
    TC* __restrict__ C, int ldc, int N, int K)
{
    __shared__ float As[64][17];
    __shared__ float Ws[64][17];
    const int tid  = threadIdx.x;
    const int bm   = blockIdx.y * 64;
    const int bn   = blockIdx.x * 64;
    const int arow = tid >> 2;
    const int ac4  = (tid & 3) << 2;
    const int tx   = tid & 15;
    const int ty   = tid >> 4;
    float acc[4][4] = {};
    const TA* Aptr = A + (size_t)(bm + arow) * lda + ac4;
    const int wrow = bn + arow;
    const float* Wptr = W + (size_t)wrow * K + ac4;
    for (int k0 = 0; k0 < K; k0 += 16) {
        float a0, a1, a2, a3;
        if constexpr (sizeof(TA) == 2) {
            ushort4 av = *(const ushort4*)(Aptr + k0);
            a0 = bf2f(av.x); a1 = bf2f(av.y); a2 = bf2f(av.z); a3 = bf2f(av.w);
        } else {
            float4 av = *(const float4*)(Aptr + k0);
            a0 = av.x; a1 = av.y; a2 = av.z; a3 = av.w;
        }
        float4 wv = make_float4(0.f, 0.f, 0.f, 0.f);
        if (wrow < N) wv = *(const float4*)(Wptr + k0);
        As[arow][ac4+0] = a0;   As[arow][ac4+1] = a1;
        As[arow][ac4+2] = a2;   As[arow][ac4+3] = a3;
        Ws[arow][ac4+0] = wv.x; Ws[arow][ac4+1] = wv.y;
        Ws[arow][ac4+2] = wv.z; Ws[arow][ac4+3] = wv.w;
        __syncthreads();
        #pragma unroll
        for (int kk = 0; kk < 16; ++kk) {
            float a[4], b[4];
            #pragma unroll
            for (int i = 0; i < 4; ++i) a[i] = As[ty*4 + i][kk];
            #pragma unroll
            for (int j = 0; j < 4; ++j) b[j] = Ws[tx*4 + j][kk];
            #pragma unroll
            for (int i = 0; i < 4; ++i)
                #pragma unroll
                for (int j = 0; j < 4; ++j)
                    acc[i][j] += a[i] * b[j];
        }
        __syncthreads();
    }
    #pragma unroll
    for (int i = 0; i < 4; ++i) {
        int row = bm + ty*4 + i;
        #pragma unroll
        for (int j = 0; j < 4; ++j) {
            int col = bn + tx*4 + j;
            if (col < N) {
                float v = acc[i][j];
                if (bias) v += bias[col];
                if (EPI == 1) { float ax = fabsf(v); v = fmaxf(v, 0.f) + log1pf(__expf(-ax)); }
                size_t off = (size_t)row * ldc + col;
                if constexpr (sizeof(TC) == 2) {
                    C[off] = f2bf(v);
                } else {
                    if (EPI == 2) v += C[off];
                    C[off] = v;
                }
            }
        }
    }
}

// ---------------- Causal depthwise conv (D_CONV=4) + SiLU ----------------
__global__ __launch_bounds__(256) void conv_silu_kernel(
    const bf16_t* __restrict__ raw, const float* __restrict__ cw,
    const float* __restrict__ cb, bf16_t* __restrict__ U)
{
    int idx = blockIdx.x * 256 + threadIdx.x;
    int d = idx % DI;
    int t = idx / DI;
    int s = t & (SEQ - 1);
    const bf16_t* base = raw + (size_t)t * DI + d;
    const float4 w = *(const float4*)(cw + d * 4);
    float acc = cb[d] + w.w * bf2f(base[0]);
    if (s >= 1) acc += w.z * bf2f(base[-DI]);
    if (s >= 2) acc += w.y * bf2f(base[-2*DI]);
    if (s >= 3) acc += w.x * bf2f(base[-3*DI]);
    U[(size_t)t * DI + d] = f2bf(acc * fast_sigmoid(acc));
}

// ---------------- Selective scan (+ D skip, * silu(z)); in-place over Z ----------------
__global__ __launch_bounds__(256) void scan_kernel(
    const bf16_t* __restrict__ U, const bf16_t* __restrict__ DT,
    const float* __restrict__ XDBL, const float* __restrict__ A_log,
    const float* __restrict__ Dp, bf16_t* __restrict__ Z)
{
    const int d = blockIdx.x * 256 + threadIdx.x;
    const int b = blockIdx.y;
    float Arow[DST];
    #pragma unroll
    for (int n = 0; n < DST; ++n) Arow[n] = -__expf(A_log[(size_t)d * DST + n]);
    const float dp = Dp[d];
    float h[DST];
    #pragma unroll
    for (int n = 0; n < DST; ++n) h[n] = 0.f;
    __shared__ float bc[64][32];
    const size_t tbase = (size_t)b * SEQ;
    for (int c0 = 0; c0 < SEQ; c0 += 64) {
        __syncthreads();
        for (int q = threadIdx.x; q < 64 * 32; q += 256) {
            int tt = q >> 5, j = q & 31;
            bc[tt][j] = XDBL[(tbase + c0 + tt) * NXP + DTR + j];
        }
        __syncthreads();
        for (int tt = 0; tt < 64; ++tt) {
            size_t t = tbase + c0 + tt;
            float ut  = bf2f(U[t * DI + d]);
            float dtt = bf2f(DT[t * DI + d]);
            float du = dtt * ut;
            float y = 0.f;
            #pragma unroll
            for (int n = 0; n < DST; ++n) {
                float dA = __expf(dtt * Arow[n]);
                h[n] = h[n] * dA + du * bc[tt][n];
                y += h[n] * bc[tt][DST + n];
            }
            y += ut * dp;
            float z = bf2f(Z[t * DI + d]);
            Z[t * DI + d] = f2bf(y * z * fast_sigmoid(z));
        }
    }
}

extern "C" void kernel_launch(void* const* d_in, const int* in_sizes, int n_in,
                              void* d_out, int out_size, void* d_ws, size_t ws_size,
                              hipStream_t stream) {
    const float* obs       = (const float*)d_in[0];
    const float* in_norm_g = (const float*)d_in[1];
    const float* in_norm_b = (const float*)d_in[2];
    const float* in_W      = (const float*)d_in[3];
    const float* in_b      = (const float*)d_in[4];
    const float* norm_g    = (const float*)d_in[5];
    const float* norm_b    = (const float*)d_in[6];
    const float* inproj_W  = (const float*)d_in[7];
    const float* conv_W    = (const float*)d_in[8];
    const float* conv_b    = (const float*)d_in[9];
    const float* xproj_W   = (const float*)d_in[10];
    const float* dt_W      = (const float*)d_in[11];
    const float* dt_b      = (const float*)d_in[12];
    const float* A_log     = (const float*)d_in[13];
    const float* D_param   = (const float*)d_in[14];
    const float* outproj_W = (const float*)d_in[15];
    const float* out_W     = (const float*)d_in[16];
    const float* out_b     = (const float*)d_in[17];
    float* out = (float*)d_out;

    // Workspace (~214 MB):
    //   X    : BS*DM  fp32 (residual)
    //   XDBL : BS*NXP fp32
    //   Z    : BS*DI  bf16 (z; scan writes gated y in-place) | aliases OBSN_bf
    //   U    : BS*DI  bf16                                   | aliases XN
    //   RAW  : BS*DI  bf16 (u_raw; then dt)
    //   WBUF : 3538944 bf16 (per-layer converted weights: inproj | outproj)
    float*  X    = (float*)d_ws;
    float*  XDBL = X + (size_t)BS * DM;
    bf16_t* Z    = (bf16_t*)(XDBL + (size_t)BS * NXP);
    bf16_t* U    = Z + (size_t)BS * DI;
    bf16_t* RAW  = U + (size_t)BS * DI;
    bf16_t* WBUF = RAW + (size_t)BS * DI;
    bf16_t* OBSN = Z;           // bf16, live only before layer loop
    bf16_t* XN   = U;           // live only between ln and inproj GEMMs
    bf16_t* WB_ip = WBUF;                          // 2*DI*DM
    bf16_t* WB_op = WBUF + (size_t)2 * DI * DM;    // DM*DI

    // 1) input layernorm + in projection (MFMA; in_W converted into WBUF)
    cvt_f2bf_kernel<<<(DM*OBSD/4 + 255)/256, 256, 0, stream>>>(in_W, WBUF, DM*OBSD/4);
    ln_kernel<bf16_t><<<BS, 256, 0, stream>>>(obs, in_norm_g, in_norm_b, OBSN, OBSD);
    gemm_mfma_kernel<float, 0><<<dim3(DM/128, BS/128), 256, 0, stream>>>(
        OBSN, OBSD, WBUF, OBSD, in_b, X, DM, OBSD);

    for (int l = 0; l < 2; ++l) {
        const float* ipW = inproj_W  + (size_t)l * (2*DI) * DM;
        const float* cW  = conv_W    + (size_t)l * DI * 4;
        const float* cB  = conv_b    + (size_t)l * DI;
        const float* xpW = xproj_W   + (size_t)l * NXP * DI;
        const float* dW  = dt_W      + (size_t)l * DI * DTR;
        const float* dB  = dt_b      + (size_t)l * DI;
        const float* Al  = A_log     + (size_t)l * DI * DST;
        const float* Dpl = D_param   + (size_t)l * DI;
        const float* opW = outproj_W + (size_t)l * DM * DI;

        // convert this layer's big weights to bf16
        cvt_f2bf_kernel<<<(2*DI*DM/4 + 255)/256, 256, 0, stream>>>(ipW, WB_ip, 2*DI*DM/4);
        cvt_f2bf_kernel<<<(DM*DI/4 + 255)/256, 256, 0, stream>>>(opW, WB_op, DM*DI/4);

        ln_kernel<bf16_t><<<BS, 256, 0, stream>>>(X, norm_g + l*DM, norm_b + l*DM, XN, DM);
        // u_raw = xn @ ipW[:DI].T
        gemm_mfma_kernel<bf16_t, 0><<<dim3(DI/128, BS/128), 256, 0, stream>>>(
            XN, DM, WB_ip, DM, nullptr, RAW, DI, DM);
        // z = xn @ ipW[DI:].T
        gemm_mfma_kernel<bf16_t, 0><<<dim3(DI/128, BS/128), 256, 0, stream>>>(
            XN, DM, WB_ip + (size_t)DI * DM, DM, nullptr, Z, DI, DM);
        // u = silu(conv(u_raw))
        conv_silu_kernel<<<(BS*DI)/256, 256, 0, stream>>>(RAW, cW, cB, U);
        // x_dbl = u @ xpW.T  (N = 80, scalar path)
        gemm_kernel<bf16_t, float, 0><<<dim3((NXP+63)/64, BS/64), 256, 0, stream>>>(
            U, DI, xpW, nullptr, XDBL, NXP, NXP, DI);
        // dt = softplus(x_dbl[:, :48] @ dtW.T + dt_b) -> RAW (K = 48, scalar path)
        gemm_kernel<float, bf16_t, 1><<<dim3(DI/64, BS/64), 256, 0, stream>>>(
            XDBL, NXP, dW, dB, RAW, DI, DI, DTR);
        // selective scan + D skip + *silu(z); result in-place into Z
        scan_kernel<<<dim3(DI/256, BATCHN), 256, 0, stream>>>(
            U, RAW, XDBL, Al, Dpl, Z);
        // x += y @ opW.T (MFMA, accumulate into fp32 X)
        gemm_mfma_kernel<float, 2><<<dim3(DM/128, BS/128), 256, 0, stream>>>(
            Z, DI, WB_op, DI, nullptr, X, DM, DI);
    }

    // out = x @ out_W.T + out_b  (N = 64, scalar path)
    gemm_kernel<float, float, 0><<<dim3(1, BS/64), 256, 0, stream>>>(
        X, DM, out_W, out_b, out, 64, 64, DM);
}

// Round 4
// 2200.415 us; speedup vs baseline: 3.6830x; 1.9690x over previous
//
#include <hip/hip_runtime.h>
#include <math.h>

#define BATCHN 8
#define SEQ    2048
#define BS     (BATCHN*SEQ)      // 16384 rows
#define OBSD   256
#define DM     768
#define DI     1536
#define DST    16
#define DTR    48
#define NXP    80                // DTR + 2*DST
#define CHK    128               // scan chunk length
#define NCHK   (SEQ/CHK)         // 16

typedef unsigned short bf16_t;
typedef __attribute__((ext_vector_type(8))) short bf16x8;
typedef __attribute__((ext_vector_type(4))) float f32x4;

__device__ __forceinline__ float bf2f(bf16_t b) {
    return __uint_as_float(((unsigned)b) << 16);
}
__device__ __forceinline__ bf16_t f2bf(float f) {
    unsigned u = __float_as_uint(f);
    unsigned r = (u + 0x7FFFu + ((u >> 16) & 1u)) >> 16;
    return (bf16_t)r;
}
__device__ __forceinline__ float fast_sigmoid(float x) {
    return __builtin_amdgcn_rcpf(1.0f + __expf(-x));
}

// ---------------- fp32 -> bf16 weight conversion ----------------
__global__ __launch_bounds__(256) void cvt_f2bf_kernel(
    const float* __restrict__ in, bf16_t* __restrict__ out, int n4)
{
    int i = blockIdx.x * 256 + threadIdx.x;
    if (i >= n4) return;
    float4 v = ((const float4*)in)[i];
    ushort4 p;
    p.x = f2bf(v.x); p.y = f2bf(v.y); p.z = f2bf(v.z); p.w = f2bf(v.w);
    ((ushort4*)out)[i] = p;
}

// ---------------- LayerNorm (one block per row), fp32 in, templated out ----------------
template<typename TOUT>
__global__ __launch_bounds__(256) void ln_kernel(
    const float* __restrict__ in, const float* __restrict__ g,
    const float* __restrict__ bta, TOUT* __restrict__ out, int D)
{
    int row = blockIdx.x;
    const float4* ip = (const float4*)(in + (size_t)row * D);
    const float4* gp = (const float4*)g;
    const float4* bp = (const float4*)bta;
    int nv = D >> 2;
    float sum = 0.f, sq = 0.f;
    for (int i = threadIdx.x; i < nv; i += 256) {
        float4 v = ip[i];
        sum += v.x + v.y + v.z + v.w;
        sq  += v.x*v.x + v.y*v.y + v.z*v.z + v.w*v.w;
    }
    for (int o = 32; o; o >>= 1) { sum += __shfl_down(sum, o); sq += __shfl_down(sq, o); }
    __shared__ float rs[4], rq[4];
    int lane = threadIdx.x & 63, wv = threadIdx.x >> 6;
    if (lane == 0) { rs[wv] = sum; rq[wv] = sq; }
    __syncthreads();
    sum = rs[0] + rs[1] + rs[2] + rs[3];
    sq  = rq[0] + rq[1] + rq[2] + rq[3];
    float inv  = 1.0f / (float)D;
    float mean = sum * inv;
    float var  = sq * inv - mean * mean;
    float rstd = rsqrtf(var + 1e-5f);
    for (int i = threadIdx.x; i < nv; i += 256) {
        float4 v = ip[i], gg = gp[i], bb = bp[i];
        float o0 = (v.x - mean) * rstd * gg.x + bb.x;
        float o1 = (v.y - mean) * rstd * gg.y + bb.y;
        float o2 = (v.z - mean) * rstd * gg.z + bb.z;
        float o3 = (v.w - mean) * rstd * gg.w + bb.w;
        if constexpr (sizeof(TOUT) == 4) {
            ((float4*)out)[(size_t)row * nv + i] = make_float4(o0, o1, o2, o3);
        } else {
            ushort4 p;
            p.x = f2bf(o0); p.y = f2bf(o1); p.z = f2bf(o2); p.w = f2bf(o3);
            ((ushort4*)out)[(size_t)row * nv + i] = p;
        }
    }
}

// ---------------- MFMA bf16 GEMM: C(M,N) = A(M,K) @ W(N,K)^T ----------------
template<typename TC, int EPI>
__global__ __launch_bounds__(256, 2) void gemm_mfma_kernel(
    const bf16_t* __restrict__ A, int lda,
    const bf16_t* __restrict__ W, int ldw,
    const float* __restrict__ bias,
    TC* __restrict__ C, int ldc, int K)
{
    const int tid  = threadIdx.x;
    const int wid  = tid >> 6;
    const int lane = tid & 63;
    const int wr   = wid >> 1, wc = wid & 1;
    const int bm   = blockIdx.y * 128 + wr * 64;
    const int bn   = blockIdx.x * 128 + wc * 64;
    const int l15  = lane & 15;
    const int kq   = lane >> 4;          // 0..3

    f32x4 acc[4][4];
    #pragma unroll
    for (int i = 0; i < 4; ++i)
        #pragma unroll
        for (int j = 0; j < 4; ++j)
            acc[i][j] = (f32x4){0.f, 0.f, 0.f, 0.f};

    const bf16_t* Ap = A + (size_t)(bm + l15) * lda + kq * 8;
    const bf16_t* Wp = W + (size_t)(bn + l15) * ldw + kq * 8;

    for (int k0 = 0; k0 < K; k0 += 32) {
        bf16x8 af[4], bf[4];
        #pragma unroll
        for (int i = 0; i < 4; ++i)
            af[i] = *(const bf16x8*)(Ap + (size_t)i * 16 * lda + k0);
        #pragma unroll
        for (int j = 0; j < 4; ++j)
            bf[j] = *(const bf16x8*)(Wp + (size_t)j * 16 * ldw + k0);
        #pragma unroll
        for (int i = 0; i < 4; ++i)
            #pragma unroll
            for (int j = 0; j < 4; ++j)
                acc[i][j] = __builtin_amdgcn_mfma_f32_16x16x32_bf16(
                    af[i], bf[j], acc[i][j], 0, 0, 0);
    }

    #pragma unroll
    for (int i = 0; i < 4; ++i) {
        int r0 = bm + i * 16 + kq * 4;
        #pragma unroll
        for (int j = 0; j < 4; ++j) {
            int col = bn + j * 16 + l15;
            float bb = bias ? bias[col] : 0.0f;
            #pragma unroll
            for (int r = 0; r < 4; ++r) {
                size_t off = (size_t)(r0 + r) * ldc + col;
                float v = acc[i][j][r] + bb;
                if constexpr (sizeof(TC) == 2) {
                    C[off] = f2bf(v);
                } else {
                    if (EPI == 2) v += C[off];
                    C[off] = v;
                }
            }
        }
    }
}

// ---------------- Scalar fp32-accum GEMM (small/odd shapes) ----------------
template<typename TA, typename TC, int EPI>
__global__ __launch_bounds__(256) void gemm_kernel(
    const TA* __restrict__ A, int lda,
    const float* __restrict__ W, const float* __restrict__ bias,
    TC* __restrict__ C, int ldc, int N, int K)
{
    __shared__ float As[64][17];
    __shared__ float Ws[64][17];
    const int tid  = threadIdx.x;
    const int bm   = blockIdx.y * 64;
    const int bn   = blockIdx.x * 64;
    const int arow = tid >> 2;
    const int ac4  = (tid & 3) << 2;
    const int tx   = tid & 15;
    const int ty   = tid >> 4;
    float acc[4][4] = {};
    const TA* Aptr = A + (size_t)(bm + arow) * lda + ac4;
    const int wrow = bn + arow;
    const float* Wptr = W + (size_t)wrow * K + ac4;
    for (int k0 = 0; k0 < K; k0 += 16) {
        float a0, a1, a2, a3;
        if constexpr (sizeof(TA) == 2) {
            ushort4 av = *(const ushort4*)(Aptr + k0);
            a0 = bf2f(av.x); a1 = bf2f(av.y); a2 = bf2f(av.z); a3 = bf2f(av.w);
        } else {
            float4 av = *(const float4*)(Aptr + k0);
            a0 = av.x; a1 = av.y; a2 = av.z; a3 = av.w;
        }
        float4 wv = make_float4(0.f, 0.f, 0.f, 0.f);
        if (wrow < N) wv = *(const float4*)(Wptr + k0);
        As[arow][ac4+0] = a0;   As[arow][ac4+1] = a1;
        As[arow][ac4+2] = a2;   As[arow][ac4+3] = a3;
        Ws[arow][ac4+0] = wv.x; Ws[arow][ac4+1] = wv.y;
        Ws[arow][ac4+2] = wv.z; Ws[arow][ac4+3] = wv.w;
        __syncthreads();
        #pragma unroll
        for (int kk = 0; kk < 16; ++kk) {
            float a[4], b[4];
            #pragma unroll
            for (int i = 0; i < 4; ++i) a[i] = As[ty*4 + i][kk];
            #pragma unroll
            for (int j = 0; j < 4; ++j) b[j] = Ws[tx*4 + j][kk];
            #pragma unroll
            for (int i = 0; i < 4; ++i)
                #pragma unroll
                for (int j = 0; j < 4; ++j)
                    acc[i][j] += a[i] * b[j];
        }
        __syncthreads();
    }
    #pragma unroll
    for (int i = 0; i < 4; ++i) {
        int row = bm + ty*4 + i;
        #pragma unroll
        for (int j = 0; j < 4; ++j) {
            int col = bn + tx*4 + j;
            if (col < N) {
                float v = acc[i][j];
                if (bias) v += bias[col];
                if (EPI == 1) { float ax = fabsf(v); v = fmaxf(v, 0.f) + log1pf(__expf(-ax)); }
                size_t off = (size_t)row * ldc + col;
                if constexpr (sizeof(TC) == 2) {
                    C[off] = f2bf(v);
                } else {
                    if (EPI == 2) v += C[off];
                    C[off] = v;
                }
            }
        }
    }
}

// ---------------- Causal depthwise conv (D_CONV=4) + SiLU ----------------
__global__ __launch_bounds__(256) void conv_silu_kernel(
    const bf16_t* __restrict__ raw, const float* __restrict__ cw,
    const float* __restrict__ cb, bf16_t* __restrict__ U)
{
    int idx = blockIdx.x * 256 + threadIdx.x;
    int d = idx % DI;
    int t = idx / DI;
    int s = t & (SEQ - 1);
    const bf16_t* base = raw + (size_t)t * DI + d;
    const float4 w = *(const float4*)(cw + d * 4);
    float acc = cb[d] + w.w * bf2f(base[0]);
    if (s >= 1) acc += w.z * bf2f(base[-DI]);
    if (s >= 2) acc += w.y * bf2f(base[-2*DI]);
    if (s >= 3) acc += w.x * bf2f(base[-3*DI]);
    U[(size_t)t * DI + d] = f2bf(acc * fast_sigmoid(acc));
}

// ---------------- Scan pass 1: per-chunk local scan -> HST (local end state), DTS (sum dt) ----
__global__ __launch_bounds__(256) void scan1_kernel(
    const bf16_t* __restrict__ U, const bf16_t* __restrict__ DT,
    const float* __restrict__ XDBL, const float* __restrict__ A_log,
    float* __restrict__ HST, float* __restrict__ DTS)
{
    const int d = blockIdx.x * 256 + threadIdx.x;
    const int c = blockIdx.y;
    const int b = blockIdx.z;
    float Arow[DST];
    #pragma unroll
    for (int n = 0; n < DST; ++n) Arow[n] = -__expf(A_log[(size_t)d * DST + n]);
    float h[DST];
    #pragma unroll
    for (int n = 0; n < DST; ++n) h[n] = 0.f;
    float dtsum = 0.f;
    __shared__ float bs[CHK][DST];
    const size_t tbase = (size_t)b * SEQ + (size_t)c * CHK;
    for (int q = threadIdx.x; q < CHK * DST; q += 256) {
        int tt = q >> 4, j = q & 15;
        bs[tt][j] = XDBL[(tbase + tt) * NXP + DTR + j];
    }
    __syncthreads();
    for (int tt = 0; tt < CHK; ++tt) {
        size_t t = tbase + tt;
        float ut  = bf2f(U[t * DI + d]);
        float dtt = bf2f(DT[t * DI + d]);
        dtsum += dtt;
        float du = dtt * ut;
        #pragma unroll
        for (int n = 0; n < DST; ++n) {
            float dA = __expf(dtt * Arow[n]);
            h[n] = h[n] * dA + du * bs[tt][n];
        }
    }
    size_t base = (((size_t)b * NCHK + c) * DI + d) * DST;
    #pragma unroll
    for (int n = 0; n < DST; ++n) HST[base + n] = h[n];
    DTS[((size_t)b * NCHK + c) * DI + d] = dtsum;
}

// ---------------- Scan pass 2: inter-chunk scan; HST overwritten with incoming state ----------
__global__ __launch_bounds__(256) void scan2_kernel(
    const float* __restrict__ A_log, const float* __restrict__ DTS,
    float* __restrict__ HST)
{
    int gid = blockIdx.x * 256 + threadIdx.x;    // over BATCHN*DI*DST
    int n = gid & 15;
    int rem = gid >> 4;                          // b*DI + d
    int d = rem % DI;
    int b = rem / DI;
    float An = -__expf(A_log[(size_t)d * DST + n]);
    float h = 0.f;
    for (int c = 0; c < NCHK; ++c) {
        size_t sidx = (((size_t)b * NCHK + c) * DI + d) * DST + n;
        float localend = HST[sidx];
        float a = __expf(An * DTS[((size_t)b * NCHK + c) * DI + d]);
        HST[sidx] = h;
        h = a * h + localend;
    }
}

// ---------------- Scan pass 3: local scan with incoming state; y+Dskip+z-gate in-place in Z ---
__global__ __launch_bounds__(256) void scan3_kernel(
    const bf16_t* __restrict__ U, const bf16_t* __restrict__ DT,
    const float* __restrict__ XDBL, const float* __restrict__ A_log,
    const float* __restrict__ Dp, const float* __restrict__ HST,
    bf16_t* __restrict__ Z)
{
    const int d = blockIdx.x * 256 + threadIdx.x;
    const int c = blockIdx.y;
    const int b = blockIdx.z;
    float Arow[DST];
    #pragma unroll
    for (int n = 0; n < DST; ++n) Arow[n] = -__expf(A_log[(size_t)d * DST + n]);
    const float dp = Dp[d];
    float h[DST];
    size_t base = (((size_t)b * NCHK + c) * DI + d) * DST;
    #pragma unroll
    for (int n = 0; n < DST; ++n) h[n] = HST[base + n];
    __shared__ float bc[CHK][2 * DST];
    const size_t tbase = (size_t)b * SEQ + (size_t)c * CHK;
    for (int q = threadIdx.x; q < CHK * 2 * DST; q += 256) {
        int tt = q >> 5, j = q & 31;
        bc[tt][j] = XDBL[(tbase + tt) * NXP + DTR + j];
    }
    __syncthreads();
    for (int tt = 0; tt < CHK; ++tt) {
        size_t t = tbase + tt;
        float ut  = bf2f(U[t * DI + d]);
        float dtt = bf2f(DT[t * DI + d]);
        float du = dtt * ut;
        float y = 0.f;
        #pragma unroll
        for (int n = 0; n < DST; ++n) {
            float dA = __expf(dtt * Arow[n]);
            h[n] = h[n] * dA + du * bc[tt][n];
            y += h[n] * bc[tt][DST + n];
        }
        y += ut * dp;
        float z = bf2f(Z[t * DI + d]);
        Z[t * DI + d] = f2bf(y * z * fast_sigmoid(z));
    }
}

extern "C" void kernel_launch(void* const* d_in, const int* in_sizes, int n_in,
                              void* d_out, int out_size, void* d_ws, size_t ws_size,
                              hipStream_t stream) {
    const float* obs       = (const float*)d_in[0];
    const float* in_norm_g = (const float*)d_in[1];
    const float* in_norm_b = (const float*)d_in[2];
    const float* in_W      = (const float*)d_in[3];
    const float* in_b      = (const float*)d_in[4];
    const float* norm_g    = (const float*)d_in[5];
    const float* norm_b    = (const float*)d_in[6];
    const float* inproj_W  = (const float*)d_in[7];
    const float* conv_W    = (const float*)d_in[8];
    const float* conv_b    = (const float*)d_in[9];
    const float* xproj_W   = (const float*)d_in[10];
    const float* dt_W      = (const float*)d_in[11];
    const float* dt_b      = (const float*)d_in[12];
    const float* A_log     = (const float*)d_in[13];
    const float* D_param   = (const float*)d_in[14];
    const float* outproj_W = (const float*)d_in[15];
    const float* out_W     = (const float*)d_in[16];
    const float* out_b     = (const float*)d_in[17];
    float* out = (float*)d_out;

    // Workspace (~226 MB):
    //   X    : BS*DM  fp32 (residual)
    //   XDBL : BS*NXP fp32
    //   Z    : BS*DI  bf16 (z; scan writes gated y in-place) | aliases OBSN
    //   U    : BS*DI  bf16                                   | aliases XN
    //   RAW  : BS*DI  bf16 (u_raw; then dt)
    //   WBUF : 3538944 bf16 (per-layer converted weights: inproj | outproj)
    //   HST  : BATCHN*NCHK*DI*DST fp32 (chunk states)
    //   DTS  : BATCHN*NCHK*DI fp32 (chunk dt sums)
    float*  X    = (float*)d_ws;
    float*  XDBL = X + (size_t)BS * DM;
    bf16_t* Z    = (bf16_t*)(XDBL + (size_t)BS * NXP);
    bf16_t* U    = Z + (size_t)BS * DI;
    bf16_t* RAW  = U + (size_t)BS * DI;
    bf16_t* WBUF = RAW + (size_t)BS * DI;
    float*  HST  = (float*)(WBUF + (size_t)3538944);
    float*  DTS  = HST + (size_t)BATCHN * NCHK * DI * DST;
    bf16_t* OBSN = Z;
    bf16_t* XN   = U;
    bf16_t* WB_ip = WBUF;                          // 2*DI*DM
    bf16_t* WB_op = WBUF + (size_t)2 * DI * DM;    // DM*DI

    // 1) input layernorm + in projection (MFMA)
    cvt_f2bf_kernel<<<(DM*OBSD/4 + 255)/256, 256, 0, stream>>>(in_W, WBUF, DM*OBSD/4);
    ln_kernel<bf16_t><<<BS, 256, 0, stream>>>(obs, in_norm_g, in_norm_b, OBSN, OBSD);
    gemm_mfma_kernel<float, 0><<<dim3(DM/128, BS/128), 256, 0, stream>>>(
        OBSN, OBSD, WBUF, OBSD, in_b, X, DM, OBSD);

    for (int l = 0; l < 2; ++l) {
        const float* ipW = inproj_W  + (size_t)l * (2*DI) * DM;
        const float* cW  = conv_W    + (size_t)l * DI * 4;
        const float* cB  = conv_b    + (size_t)l * DI;
        const float* xpW = xproj_W   + (size_t)l * NXP * DI;
        const float* dW  = dt_W      + (size_t)l * DI * DTR;
        const float* dB  = dt_b      + (size_t)l * DI;
        const float* Al  = A_log     + (size_t)l * DI * DST;
        const float* Dpl = D_param   + (size_t)l * DI;
        const float* opW = outproj_W + (size_t)l * DM * DI;

        cvt_f2bf_kernel<<<(2*DI*DM/4 + 255)/256, 256, 0, stream>>>(ipW, WB_ip, 2*DI*DM/4);
        cvt_f2bf_kernel<<<(DM*DI/4 + 255)/256, 256, 0, stream>>>(opW, WB_op, DM*DI/4);

        ln_kernel<bf16_t><<<BS, 256, 0, stream>>>(X, norm_g + l*DM, norm_b + l*DM, XN, DM);
        gemm_mfma_kernel<bf16_t, 0><<<dim3(DI/128, BS/128), 256, 0, stream>>>(
            XN, DM, WB_ip, DM, nullptr, RAW, DI, DM);
        gemm_mfma_kernel<bf16_t, 0><<<dim3(DI/128, BS/128), 256, 0, stream>>>(
            XN, DM, WB_ip + (size_t)DI * DM, DM, nullptr, Z, DI, DM);
        conv_silu_kernel<<<(BS*DI)/256, 256, 0, stream>>>(RAW, cW, cB, U);
        gemm_kernel<bf16_t, float, 0><<<dim3((NXP+63)/64, BS/64), 256, 0, stream>>>(
            U, DI, xpW, nullptr, XDBL, NXP, NXP, DI);
        gemm_kernel<float, bf16_t, 1><<<dim3(DI/64, BS/64), 256, 0, stream>>>(
            XDBL, NXP, dW, dB, RAW, DI, DI, DTR);
        // three-pass chunked selective scan
        scan1_kernel<<<dim3(DI/256, NCHK, BATCHN), 256, 0, stream>>>(
            U, RAW, XDBL, Al, HST, DTS);
        scan2_kernel<<<(BATCHN*DI*DST)/256, 256, 0, stream>>>(Al, DTS, HST);
        scan3_kernel<<<dim3(DI/256, NCHK, BATCHN), 256, 0, stream>>>(
            U, RAW, XDBL, Al, Dpl, HST, Z);
        // x += y @ opW.T (MFMA, accumulate into fp32 X)
        gemm_mfma_kernel<float, 2><<<dim3(DM/128, BS/128), 256, 0, stream>>>(
            Z, DI, WB_op, DI, nullptr, X, DM, DI);
    }

    // out = x @ out_W.T + out_b  (N = 64, scalar path)
    gemm_kernel<float, float, 0><<<dim3(1, BS/64), 256, 0, stream>>>(
        X, DM, out_W, out_b, out, 64, 64, DM);
}

// Round 5
// 1451.607 us; speedup vs baseline: 5.5828x; 1.5158x over previous
//
#include <hip/hip_runtime.h>
#include <math.h>

#define BATCHN 8
#define SEQ    2048
#define BS     (BATCHN*SEQ)      // 16384 rows
#define OBSD   256
#define DM     768
#define DI     1536
#define DST    16
#define DTR    48
#define NXP    80                // DTR + 2*DST
#define CHK    128               // scan chunk length
#define NCHK   (SEQ/CHK)         // 16

typedef unsigned short bf16_t;
typedef __attribute__((ext_vector_type(8))) short bf16x8;
typedef __attribute__((ext_vector_type(4))) float f32x4;

__device__ __forceinline__ float bf2f(bf16_t b) {
    return __uint_as_float(((unsigned)b) << 16);
}
__device__ __forceinline__ bf16_t f2bf(float f) {
    unsigned u = __float_as_uint(f);
    unsigned r = (u + 0x7FFFu + ((u >> 16) & 1u)) >> 16;
    return (bf16_t)r;
}
__device__ __forceinline__ float fast_sigmoid(float x) {
    return __builtin_amdgcn_rcpf(1.0f + __expf(-x));
}
__device__ __forceinline__ bf16x8 pack8(float4 f0, float4 f1) {
    bf16x8 r;
    r[0] = (short)f2bf(f0.x); r[1] = (short)f2bf(f0.y);
    r[2] = (short)f2bf(f0.z); r[3] = (short)f2bf(f0.w);
    r[4] = (short)f2bf(f1.x); r[5] = (short)f2bf(f1.y);
    r[6] = (short)f2bf(f1.z); r[7] = (short)f2bf(f1.w);
    return r;
}

// ---------------- fp32 -> bf16 weight conversion ----------------
__global__ __launch_bounds__(256) void cvt_f2bf_kernel(
    const float* __restrict__ in, bf16_t* __restrict__ out, int n4)
{
    int i = blockIdx.x * 256 + threadIdx.x;
    if (i >= n4) return;
    float4 v = ((const float4*)in)[i];
    ushort4 p;
    p.x = f2bf(v.x); p.y = f2bf(v.y); p.z = f2bf(v.z); p.w = f2bf(v.w);
    ((ushort4*)out)[i] = p;
}

// ---------------- LayerNorm (one block per row), fp32 in, templated out ----------------
template<typename TOUT>
__global__ __launch_bounds__(256) void ln_kernel(
    const float* __restrict__ in, const float* __restrict__ g,
    const float* __restrict__ bta, TOUT* __restrict__ out, int D)
{
    int row = blockIdx.x;
    const float4* ip = (const float4*)(in + (size_t)row * D);
    const float4* gp = (const float4*)g;
    const float4* bp = (const float4*)bta;
    int nv = D >> 2;
    float sum = 0.f, sq = 0.f;
    for (int i = threadIdx.x; i < nv; i += 256) {
        float4 v = ip[i];
        sum += v.x + v.y + v.z + v.w;
        sq  += v.x*v.x + v.y*v.y + v.z*v.z + v.w*v.w;
    }
    for (int o = 32; o; o >>= 1) { sum += __shfl_down(sum, o); sq += __shfl_down(sq, o); }
    __shared__ float rs[4], rq[4];
    int lane = threadIdx.x & 63, wv = threadIdx.x >> 6;
    if (lane == 0) { rs[wv] = sum; rq[wv] = sq; }
    __syncthreads();
    sum = rs[0] + rs[1] + rs[2] + rs[3];
    sq  = rq[0] + rq[1] + rq[2] + rq[3];
    float inv  = 1.0f / (float)D;
    float mean = sum * inv;
    float var  = sq * inv - mean * mean;
    float rstd = rsqrtf(var + 1e-5f);
    for (int i = threadIdx.x; i < nv; i += 256) {
        float4 v = ip[i], gg = gp[i], bb = bp[i];
        float o0 = (v.x - mean) * rstd * gg.x + bb.x;
        float o1 = (v.y - mean) * rstd * gg.y + bb.y;
        float o2 = (v.z - mean) * rstd * gg.z + bb.z;
        float o3 = (v.w - mean) * rstd * gg.w + bb.w;
        if constexpr (sizeof(TOUT) == 4) {
            ((float4*)out)[(size_t)row * nv + i] = make_float4(o0, o1, o2, o3);
        } else {
            ushort4 p;
            p.x = f2bf(o0); p.y = f2bf(o1); p.z = f2bf(o2); p.w = f2bf(o3);
            ((ushort4*)out)[(size_t)row * nv + i] = p;
        }
    }
}

// ---------------- LDS-staged MFMA bf16 GEMM (m97 structure + T2 swizzle) ----------------
// C(M,N) = A(M,K) @ W(N,K)^T. Block 128x128 (4 waves 2x2, wave 64x64), BK=64.
// Staging: global_load_lds 16B, linear LDS dest; XOR-swizzle byte^=((row&7)<<4)
// applied to the GLOBAL source address and to the ds_read address (both-sides rule).
// Requires M%128==0, N%128==0, K%64==0.
template<typename TC, int EPI>
__global__ __launch_bounds__(256, 2) void gemm_lds_kernel(
    const bf16_t* __restrict__ A, int lda,
    const bf16_t* __restrict__ W, int ldw,
    const float* __restrict__ bias,
    TC* __restrict__ C, int ldc, int K)
{
    __shared__ __align__(16) bf16_t As[128 * 64];
    __shared__ __align__(16) bf16_t Ws[128 * 64];
    const int tid  = threadIdx.x;
    const int wv   = tid >> 6;
    const int lane = tid & 63;
    const int wr   = wv >> 1, wc = wv & 1;
    const int bm   = blockIdx.y * 128;
    const int bn   = blockIdx.x * 128;
    const int l15  = lane & 15;
    const int kq   = lane >> 4;

    f32x4 acc[4][4];
    #pragma unroll
    for (int i = 0; i < 4; ++i)
        #pragma unroll
        for (int j = 0; j < 4; ++j)
            acc[i][j] = (f32x4){0.f, 0.f, 0.f, 0.f};

    // staging address precompute: 4 issues per wave per tile (16 issues x 1KB = 16KB)
    int rowS[4], kbS[4], ldsO[4];
    #pragma unroll
    for (int q = 0; q < 4; ++q) {
        int o  = (wv * 4 + q) * 1024 + lane * 16;   // linear LDS byte offset
        int ol = o ^ (((o >> 7) & 7) << 4);         // logical position (involution)
        rowS[q] = ol >> 7;                          // tile row 0..127
        kbS[q]  = ol & 127;                         // byte within row (k*2)
        ldsO[q] = (wv * 4 + q) * 1024;
    }

    const char* Ab  = (const char*)A;
    const char* Wb  = (const char*)W;
    char*       AsB = (char*)As;
    char*       WsB = (char*)Ws;

    for (int k0 = 0; k0 < K; k0 += 64) {
        #pragma unroll
        for (int q = 0; q < 4; ++q) {
            const void* ga = Ab + ((size_t)(bm + rowS[q]) * lda + k0) * 2 + kbS[q];
            const void* gw = Wb + ((size_t)(bn + rowS[q]) * ldw + k0) * 2 + kbS[q];
            __builtin_amdgcn_global_load_lds(
                (const __attribute__((address_space(1))) unsigned*)ga,
                (__attribute__((address_space(3))) unsigned*)(AsB + ldsO[q]), 16, 0, 0);
            __builtin_amdgcn_global_load_lds(
                (const __attribute__((address_space(1))) unsigned*)gw,
                (__attribute__((address_space(3))) unsigned*)(WsB + ldsO[q]), 16, 0, 0);
        }
        __syncthreads();   // compiler drains vmcnt before s_barrier -> LDS valid
        #pragma unroll
        for (int ks = 0; ks < 64; ks += 32) {
            bf16x8 af[4], bf[4];
            #pragma unroll
            for (int i = 0; i < 4; ++i) {
                int r  = wr * 64 + i * 16 + l15;
                int la = r * 128 + ks * 2 + kq * 16;
                af[i] = *(const bf16x8*)(AsB + (la ^ ((r & 7) << 4)));
            }
            #pragma unroll
            for (int j = 0; j < 4; ++j) {
                int r  = wc * 64 + j * 16 + l15;
                int la = r * 128 + ks * 2 + kq * 16;
                bf[j] = *(const bf16x8*)(WsB + (la ^ ((r & 7) << 4)));
            }
            #pragma unroll
            for (int i = 0; i < 4; ++i)
                #pragma unroll
                for (int j = 0; j < 4; ++j)
                    acc[i][j] = __builtin_amdgcn_mfma_f32_16x16x32_bf16(
                        af[i], bf[j], acc[i][j], 0, 0, 0);
        }
        __syncthreads();
    }

    #pragma unroll
    for (int i = 0; i < 4; ++i) {
        int r0 = bm + wr * 64 + i * 16 + kq * 4;
        #pragma unroll
        for (int j = 0; j < 4; ++j) {
            int col = bn + wc * 64 + j * 16 + l15;
            float bb = bias ? bias[col] : 0.0f;
            #pragma unroll
            for (int r = 0; r < 4; ++r) {
                size_t off = (size_t)(r0 + r) * ldc + col;
                float v = acc[i][j][r] + bb;
                if constexpr (sizeof(TC) == 2) {
                    C[off] = f2bf(v);
                } else {
                    if (EPI == 2) v += C[off];
                    C[off] = v;
                }
            }
        }
    }
}

// ---------------- Small-N direct MFMA GEMM: C(M,N) = A(M,K) @ W(N,K)^T ----------------
// W is fp32, converted in-register. Wave tile 16 x (NF*16); block = 4 waves = 64 rows.
// grid = (N/(NF*16), M/64). K arbitrary multiple of 8 (zero-padded to 32-granularity).
// EPI: 0 none, 1 +bias, 2 softplus(+bias).
template<int NF, typename TA, typename TC, int EPI>
__global__ __launch_bounds__(256) void gemm_smalln_kernel(
    const TA* __restrict__ A, int lda,
    const float* __restrict__ W, int ldw,
    const float* __restrict__ bias,
    TC* __restrict__ C, int ldc, int K)
{
    const int tid  = threadIdx.x;
    const int wv   = tid >> 6;
    const int lane = tid & 63;
    const int l15  = lane & 15;
    const int kq   = lane >> 4;
    const int row  = blockIdx.y * 64 + wv * 16 + l15;
    const int bn   = blockIdx.x * (NF * 16);
    const bf16x8 zero8 = {0,0,0,0,0,0,0,0};

    f32x4 acc[NF];
    #pragma unroll
    for (int j = 0; j < NF; ++j) acc[j] = (f32x4){0.f, 0.f, 0.f, 0.f};

    for (int k0 = 0; k0 < K; k0 += 32) {
        int kk = k0 + kq * 8;
        bool kv = kk < K;            // all uses have K%8==0, so kv => 8 full elems
        int ko = kv ? kk : 0;        // safe address for masked lanes
        bf16x8 a;
        if constexpr (sizeof(TA) == 2) {
            a = *(const bf16x8*)(A + (size_t)row * lda + ko);
        } else {
            const float* ap = A + (size_t)row * lda + ko;
            a = pack8(*(const float4*)ap, *(const float4*)(ap + 4));
        }
        if (!kv) a = zero8;
        bf16x8 b[NF];
        #pragma unroll
        for (int j = 0; j < NF; ++j) {
            int n = bn + j * 16 + l15;
            const float* wp = W + (size_t)n * ldw + ko;
            b[j] = pack8(*(const float4*)wp, *(const float4*)(wp + 4));
            if (!kv) b[j] = zero8;
        }
        #pragma unroll
        for (int j = 0; j < NF; ++j)
            acc[j] = __builtin_amdgcn_mfma_f32_16x16x32_bf16(a, b[j], acc[j], 0, 0, 0);
    }

    const int r0 = blockIdx.y * 64 + wv * 16 + kq * 4;
    #pragma unroll
    for (int j = 0; j < NF; ++j) {
        int col = bn + j * 16 + l15;
        float bb = bias ? bias[col] : 0.0f;
        #pragma unroll
        for (int r = 0; r < 4; ++r) {
            float v = acc[j][r] + bb;
            if (EPI == 2) { float ax = fabsf(v); v = fmaxf(v, 0.f) + log1pf(__expf(-ax)); }
            size_t off = (size_t)(r0 + r) * ldc + col;
            if constexpr (sizeof(TC) == 2) C[off] = f2bf(v);
            else                           C[off] = v;
        }
    }
}

// ---------------- Causal depthwise conv (D_CONV=4) + SiLU ----------------
__global__ __launch_bounds__(256) void conv_silu_kernel(
    const bf16_t* __restrict__ raw, const float* __restrict__ cw,
    const float* __restrict__ cb, bf16_t* __restrict__ U)
{
    int idx = blockIdx.x * 256 + threadIdx.x;
    int d = idx % DI;
    int t = idx / DI;
    int s = t & (SEQ - 1);
    const bf16_t* base = raw + (size_t)t * DI + d;
    const float4 w = *(const float4*)(cw + d * 4);
    float acc = cb[d] + w.w * bf2f(base[0]);
    if (s >= 1) acc += w.z * bf2f(base[-DI]);
    if (s >= 2) acc += w.y * bf2f(base[-2*DI]);
    if (s >= 3) acc += w.x * bf2f(base[-3*DI]);
    U[(size_t)t * DI + d] = f2bf(acc * fast_sigmoid(acc));
}

// ---------------- Scan pass 1: per-chunk local scan -> HST (local end state), DTS ----------
__global__ __launch_bounds__(256) void scan1_kernel(
    const bf16_t* __restrict__ U, const bf16_t* __restrict__ DT,
    const float* __restrict__ XDBL, const float* __restrict__ A_log,
    float* __restrict__ HST, float* __restrict__ DTS)
{
    const int d = blockIdx.x * 256 + threadIdx.x;
    const int c = blockIdx.y;
    const int b = blockIdx.z;
    float Arow[DST];
    #pragma unroll
    for (int n = 0; n < DST; ++n) Arow[n] = -__expf(A_log[(size_t)d * DST + n]);
    float h[DST];
    #pragma unroll
    for (int n = 0; n < DST; ++n) h[n] = 0.f;
    float dtsum = 0.f;
    __shared__ float bs[CHK][DST];
    const size_t tbase = (size_t)b * SEQ + (size_t)c * CHK;
    for (int q = threadIdx.x; q < CHK * DST; q += 256) {
        int tt = q >> 4, j = q & 15;
        bs[tt][j] = XDBL[(tbase + tt) * NXP + DTR + j];
    }
    __syncthreads();
    for (int tt = 0; tt < CHK; ++tt) {
        size_t t = tbase + tt;
        float ut  = bf2f(U[t * DI + d]);
        float dtt = bf2f(DT[t * DI + d]);
        dtsum += dtt;
        float du = dtt * ut;
        #pragma unroll
        for (int n = 0; n < DST; ++n) {
            float dA = __expf(dtt * Arow[n]);
            h[n] = h[n] * dA + du * bs[tt][n];
        }
    }
    size_t base = (((size_t)b * NCHK + c) * DI + d) * DST;
    #pragma unroll
    for (int n = 0; n < DST; ++n) HST[base + n] = h[n];
    DTS[((size_t)b * NCHK + c) * DI + d] = dtsum;
}

// ---------------- Scan pass 2: inter-chunk scan; HST -> incoming state ----------
__global__ __launch_bounds__(256) void scan2_kernel(
    const float* __restrict__ A_log, const float* __restrict__ DTS,
    float* __restrict__ HST)
{
    int gid = blockIdx.x * 256 + threadIdx.x;    // over BATCHN*DI*DST
    int n = gid & 15;
    int rem = gid >> 4;
    int d = rem % DI;
    int b = rem / DI;
    float An = -__expf(A_log[(size_t)d * DST + n]);
    float h = 0.f;
    for (int c = 0; c < NCHK; ++c) {
        size_t sidx = (((size_t)b * NCHK + c) * DI + d) * DST + n;
        float localend = HST[sidx];
        float a = __expf(An * DTS[((size_t)b * NCHK + c) * DI + d]);
        HST[sidx] = h;
        h = a * h + localend;
    }
}

// ---------------- Scan pass 3: local scan + y + Dskip + z-gate in-place in Z ---------------
__global__ __launch_bounds__(256) void scan3_kernel(
    const bf16_t* __restrict__ U, const bf16_t* __restrict__ DT,
    const float* __restrict__ XDBL, const float* __restrict__ A_log,
    const float* __restrict__ Dp, const float* __restrict__ HST,
    bf16_t* __restrict__ Z)
{
    const int d = blockIdx.x * 256 + threadIdx.x;
    const int c = blockIdx.y;
    const int b = blockIdx.z;
    float Arow[DST];
    #pragma unroll
    for (int n = 0; n < DST; ++n) Arow[n] = -__expf(A_log[(size_t)d * DST + n]);
    const float dp = Dp[d];
    float h[DST];
    size_t base = (((size_t)b * NCHK + c) * DI + d) * DST;
    #pragma unroll
    for (int n = 0; n < DST; ++n) h[n] = HST[base + n];
    __shared__ float bc[CHK][2 * DST];
    const size_t tbase = (size_t)b * SEQ + (size_t)c * CHK;
    for (int q = threadIdx.x; q < CHK * 2 * DST; q += 256) {
        int tt = q >> 5, j = q & 31;
        bc[tt][j] = XDBL[(tbase + tt) * NXP + DTR + j];
    }
    __syncthreads();
    for (int tt = 0; tt < CHK; ++tt) {
        size_t t = tbase + tt;
        float ut  = bf2f(U[t * DI + d]);
        float dtt = bf2f(DT[t * DI + d]);
        float du = dtt * ut;
        float y = 0.f;
        #pragma unroll
        for (int n = 0; n < DST; ++n) {
            float dA = __expf(dtt * Arow[n]);
            h[n] = h[n] * dA + du * bc[tt][n];
            y += h[n] * bc[tt][DST + n];
        }
        y += ut * dp;
        float z = bf2f(Z[t * DI + d]);
        Z[t * DI + d] = f2bf(y * z * fast_sigmoid(z));
    }
}

extern "C" void kernel_launch(void* const* d_in, const int* in_sizes, int n_in,
                              void* d_out, int out_size, void* d_ws, size_t ws_size,
                              hipStream_t stream) {
    const float* obs       = (const float*)d_in[0];
    const float* in_norm_g = (const float*)d_in[1];
    const float* in_norm_b = (const float*)d_in[2];
    const float* in_W      = (const float*)d_in[3];
    const float* in_b      = (const float*)d_in[4];
    const float* norm_g    = (const float*)d_in[5];
    const float* norm_b    = (const float*)d_in[6];
    const float* inproj_W  = (const float*)d_in[7];
    const float* conv_W    = (const float*)d_in[8];
    const float* conv_b    = (const float*)d_in[9];
    const float* xproj_W   = (const float*)d_in[10];
    const float* dt_W      = (const float*)d_in[11];
    const float* dt_b      = (const float*)d_in[12];
    const float* A_log     = (const float*)d_in[13];
    const float* D_param   = (const float*)d_in[14];
    const float* outproj_W = (const float*)d_in[15];
    const float* out_W     = (const float*)d_in[16];
    const float* out_b     = (const float*)d_in[17];
    float* out = (float*)d_out;

    // Workspace (~226 MB): X | XDBL | Z | U | RAW | WBUF | HST | DTS
    float*  X    = (float*)d_ws;
    float*  XDBL = X + (size_t)BS * DM;
    bf16_t* Z    = (bf16_t*)(XDBL + (size_t)BS * NXP);
    bf16_t* U    = Z + (size_t)BS * DI;
    bf16_t* RAW  = U + (size_t)BS * DI;
    bf16_t* WBUF = RAW + (size_t)BS * DI;
    float*  HST  = (float*)(WBUF + (size_t)3538944);
    float*  DTS  = HST + (size_t)BATCHN * NCHK * DI * DST;
    bf16_t* OBSN = Z;           // live only before layer loop
    bf16_t* XN   = U;           // live only between ln and inproj GEMMs
    bf16_t* WB_ip = WBUF;                          // 2*DI*DM
    bf16_t* WB_op = WBUF + (size_t)2 * DI * DM;    // DM*DI

    // 1) input layernorm + in projection (small-N MFMA, fp32 W direct)
    ln_kernel<bf16_t><<<BS, 256, 0, stream>>>(obs, in_norm_g, in_norm_b, OBSN, OBSD);
    gemm_smalln_kernel<4, bf16_t, float, 1><<<dim3(DM/64, BS/64), 256, 0, stream>>>(
        OBSN, OBSD, in_W, OBSD, in_b, X, DM, OBSD);

    for (int l = 0; l < 2; ++l) {
        const float* ipW = inproj_W  + (size_t)l * (2*DI) * DM;
        const float* cW  = conv_W    + (size_t)l * DI * 4;
        const float* cB  = conv_b    + (size_t)l * DI;
        const float* xpW = xproj_W   + (size_t)l * NXP * DI;
        const float* dW  = dt_W      + (size_t)l * DI * DTR;
        const float* dB  = dt_b      + (size_t)l * DI;
        const float* Al  = A_log     + (size_t)l * DI * DST;
        const float* Dpl = D_param   + (size_t)l * DI;
        const float* opW = outproj_W + (size_t)l * DM * DI;

        cvt_f2bf_kernel<<<(2*DI*DM/4 + 255)/256, 256, 0, stream>>>(ipW, WB_ip, 2*DI*DM/4);
        cvt_f2bf_kernel<<<(DM*DI/4 + 255)/256, 256, 0, stream>>>(opW, WB_op, DM*DI/4);

        ln_kernel<bf16_t><<<BS, 256, 0, stream>>>(X, norm_g + l*DM, norm_b + l*DM, XN, DM);
        // u_raw = xn @ ipW[:DI].T       (LDS-staged MFMA)
        gemm_lds_kernel<bf16_t, 0><<<dim3(DI/128, BS/128), 256, 0, stream>>>(
            XN, DM, WB_ip, DM, nullptr, RAW, DI, DM);
        // z = xn @ ipW[DI:].T
        gemm_lds_kernel<bf16_t, 0><<<dim3(DI/128, BS/128), 256, 0, stream>>>(
            XN, DM, WB_ip + (size_t)DI * DM, DM, nullptr, Z, DI, DM);
        // u = silu(conv(u_raw))
        conv_silu_kernel<<<(BS*DI)/256, 256, 0, stream>>>(RAW, cW, cB, U);
        // x_dbl = u @ xpW.T  (N = 80 exact: NF=5)
        gemm_smalln_kernel<5, bf16_t, float, 0><<<dim3(1, BS/64), 256, 0, stream>>>(
            U, DI, xpW, DI, nullptr, XDBL, NXP, DI);
        // dt = softplus(x_dbl[:, :48] @ dtW.T + dt_b) -> RAW  (K=48 padded)
        gemm_smalln_kernel<4, float, bf16_t, 2><<<dim3(DI/64, BS/64), 256, 0, stream>>>(
            XDBL, NXP, dW, DTR, dB, RAW, DI, DTR);
        // three-pass chunked selective scan
        scan1_kernel<<<dim3(DI/256, NCHK, BATCHN), 256, 0, stream>>>(
            U, RAW, XDBL, Al, HST, DTS);
        scan2_kernel<<<(BATCHN*DI*DST)/256, 256, 0, stream>>>(Al, DTS, HST);
        scan3_kernel<<<dim3(DI/256, NCHK, BATCHN), 256, 0, stream>>>(
            U, RAW, XDBL, Al, Dpl, HST, Z);
        // x += y @ opW.T (LDS-staged MFMA, accumulate into fp32 X)
        gemm_lds_kernel<float, 2><<<dim3(DM/128, BS/128), 256, 0, stream>>>(
            Z, DI, WB_op, DI, nullptr, X, DM, DI);
    }

    // out = x @ out_W.T + out_b  (N = 64 exact: NF=4)
    gemm_smalln_kernel<4, float, float, 1><<<dim3(1, BS/64), 256, 0, stream>>>(
        X, DM, out_W, DM, out_b, out, 64, DM);
}

// Round 6
// 1373.061 us; speedup vs baseline: 5.9022x; 1.0572x over previous
//
#include <hip/hip_runtime.h>
#include <math.h>

#define BATCHN 8
#define SEQ    2048
#define BS     (BATCHN*SEQ)      // 16384 rows
#define OBSD   256
#define DM     768
#define DI     1536
#define DST    16
#define DTR    48
#define NXP    80                // DTR + 2*DST
#define CHK    128               // scan chunk length
#define NCHK   (SEQ/CHK)         // 16

typedef unsigned short bf16_t;
typedef __attribute__((ext_vector_type(8))) short bf16x8;
typedef __attribute__((ext_vector_type(4))) float f32x4;

__device__ __forceinline__ float bf2f(bf16_t b) {
    return __uint_as_float(((unsigned)b) << 16);
}
__device__ __forceinline__ bf16_t f2bf(float f) {
    unsigned u = __float_as_uint(f);
    unsigned r = (u + 0x7FFFu + ((u >> 16) & 1u)) >> 16;
    return (bf16_t)r;
}
__device__ __forceinline__ float fast_sigmoid(float x) {
    return __builtin_amdgcn_rcpf(1.0f + __expf(-x));
}
__device__ __forceinline__ bf16x8 pack8(float4 f0, float4 f1) {
    bf16x8 r;
    r[0] = (short)f2bf(f0.x); r[1] = (short)f2bf(f0.y);
    r[2] = (short)f2bf(f0.z); r[3] = (short)f2bf(f0.w);
    r[4] = (short)f2bf(f1.x); r[5] = (short)f2bf(f1.y);
    r[6] = (short)f2bf(f1.z); r[7] = (short)f2bf(f1.w);
    return r;
}

// ---------------- fp32 -> bf16 weight conversion ----------------
__global__ __launch_bounds__(256) void cvt_f2bf_kernel(
    const float* __restrict__ in, bf16_t* __restrict__ out, int n4)
{
    int i = blockIdx.x * 256 + threadIdx.x;
    if (i >= n4) return;
    float4 v = ((const float4*)in)[i];
    ushort4 p;
    p.x = f2bf(v.x); p.y = f2bf(v.y); p.z = f2bf(v.z); p.w = f2bf(v.w);
    ((ushort4*)out)[i] = p;
}

// ---------------- LayerNorm (one block per row), fp32 in, templated out ----------------
template<typename TOUT>
__global__ __launch_bounds__(256) void ln_kernel(
    const float* __restrict__ in, const float* __restrict__ g,
    const float* __restrict__ bta, TOUT* __restrict__ out, int D)
{
    int row = blockIdx.x;
    const float4* ip = (const float4*)(in + (size_t)row * D);
    const float4* gp = (const float4*)g;
    const float4* bp = (const float4*)bta;
    int nv = D >> 2;
    float sum = 0.f, sq = 0.f;
    for (int i = threadIdx.x; i < nv; i += 256) {
        float4 v = ip[i];
        sum += v.x + v.y + v.z + v.w;
        sq  += v.x*v.x + v.y*v.y + v.z*v.z + v.w*v.w;
    }
    for (int o = 32; o; o >>= 1) { sum += __shfl_down(sum, o); sq += __shfl_down(sq, o); }
    __shared__ float rs[4], rq[4];
    int lane = threadIdx.x & 63, wv = threadIdx.x >> 6;
    if (lane == 0) { rs[wv] = sum; rq[wv] = sq; }
    __syncthreads();
    sum = rs[0] + rs[1] + rs[2] + rs[3];
    sq  = rq[0] + rq[1] + rq[2] + rq[3];
    float inv  = 1.0f / (float)D;
    float mean = sum * inv;
    float var  = sq * inv - mean * mean;
    float rstd = rsqrtf(var + 1e-5f);
    for (int i = threadIdx.x; i < nv; i += 256) {
        float4 v = ip[i], gg = gp[i], bb = bp[i];
        float o0 = (v.x - mean) * rstd * gg.x + bb.x;
        float o1 = (v.y - mean) * rstd * gg.y + bb.y;
        float o2 = (v.z - mean) * rstd * gg.z + bb.z;
        float o3 = (v.w - mean) * rstd * gg.w + bb.w;
        if constexpr (sizeof(TOUT) == 4) {
            ((float4*)out)[(size_t)row * nv + i] = make_float4(o0, o1, o2, o3);
        } else {
            ushort4 p;
            p.x = f2bf(o0); p.y = f2bf(o1); p.z = f2bf(o2); p.w = f2bf(o3);
            ((ushort4*)out)[(size_t)row * nv + i] = p;
        }
    }
}

// ---------------- LDS-staged MFMA bf16 GEMM (m97 structure + T2 swizzle + T1 XCD swizzle) ---
// C(M,N) = A(M,K) @ W(N,K)^T. Block 128x128 (4 waves 2x2, wave 64x64), BK=64.
// Requires M%128==0, N%128==0, K%64==0, (gridX*gridY)%8==0.
template<typename TC, int EPI>
__global__ __launch_bounds__(256, 2) void gemm_lds_kernel(
    const bf16_t* __restrict__ A, int lda,
    const bf16_t* __restrict__ W, int ldw,
    const float* __restrict__ bias,
    TC* __restrict__ C, int ldc, int K)
{
    __shared__ __align__(16) bf16_t As[128 * 64];
    __shared__ __align__(16) bf16_t Ws[128 * 64];
    const int tid  = threadIdx.x;
    const int wv   = tid >> 6;
    const int lane = tid & 63;
    const int wr   = wv >> 1, wc = wv & 1;
    // bijective XCD swizzle (nwg % 8 == 0 for all our grids)
    const int nx   = gridDim.x;
    const int nwg  = nx * gridDim.y;
    const int flat = blockIdx.y * nx + blockIdx.x;
    const int cpx  = nwg >> 3;
    const int swz  = (flat & 7) * cpx + (flat >> 3);
    const int bm   = (swz / nx) * 128;
    const int bn   = (swz % nx) * 128;
    const int l15  = lane & 15;
    const int kq   = lane >> 4;

    f32x4 acc[4][4];
    #pragma unroll
    for (int i = 0; i < 4; ++i)
        #pragma unroll
        for (int j = 0; j < 4; ++j)
            acc[i][j] = (f32x4){0.f, 0.f, 0.f, 0.f};

    // staging: 4 issues per wave per operand tile; linear LDS dest,
    // inverse-swizzled global source (both-sides rule)
    int rowS[4], kbS[4], ldsO[4];
    #pragma unroll
    for (int q = 0; q < 4; ++q) {
        int o  = (wv * 4 + q) * 1024 + lane * 16;
        int ol = o ^ (((o >> 7) & 7) << 4);
        rowS[q] = ol >> 7;
        kbS[q]  = ol & 127;
        ldsO[q] = (wv * 4 + q) * 1024;
    }

    const char* Ab  = (const char*)A;
    const char* Wb  = (const char*)W;
    char*       AsB = (char*)As;
    char*       WsB = (char*)Ws;

    for (int k0 = 0; k0 < K; k0 += 64) {
        #pragma unroll
        for (int q = 0; q < 4; ++q) {
            const void* ga = Ab + ((size_t)(bm + rowS[q]) * lda + k0) * 2 + kbS[q];
            const void* gw = Wb + ((size_t)(bn + rowS[q]) * ldw + k0) * 2 + kbS[q];
            __builtin_amdgcn_global_load_lds(
                (const __attribute__((address_space(1))) unsigned*)ga,
                (__attribute__((address_space(3))) unsigned*)(AsB + ldsO[q]), 16, 0, 0);
            __builtin_amdgcn_global_load_lds(
                (const __attribute__((address_space(1))) unsigned*)gw,
                (__attribute__((address_space(3))) unsigned*)(WsB + ldsO[q]), 16, 0, 0);
        }
        __syncthreads();
        #pragma unroll
        for (int ks = 0; ks < 64; ks += 32) {
            bf16x8 af[4], bf[4];
            #pragma unroll
            for (int i = 0; i < 4; ++i) {
                int r  = wr * 64 + i * 16 + l15;
                int la = r * 128 + ks * 2 + kq * 16;
                af[i] = *(const bf16x8*)(AsB + (la ^ ((r & 7) << 4)));
            }
            #pragma unroll
            for (int j = 0; j < 4; ++j) {
                int r  = wc * 64 + j * 16 + l15;
                int la = r * 128 + ks * 2 + kq * 16;
                bf[j] = *(const bf16x8*)(WsB + (la ^ ((r & 7) << 4)));
            }
            #pragma unroll
            for (int i = 0; i < 4; ++i)
                #pragma unroll
                for (int j = 0; j < 4; ++j)
                    acc[i][j] = __builtin_amdgcn_mfma_f32_16x16x32_bf16(
                        af[i], bf[j], acc[i][j], 0, 0, 0);
        }
        __syncthreads();
    }

    #pragma unroll
    for (int i = 0; i < 4; ++i) {
        int r0 = bm + wr * 64 + i * 16 + kq * 4;
        #pragma unroll
        for (int j = 0; j < 4; ++j) {
            int col = bn + wc * 64 + j * 16 + l15;
            float bb = bias ? bias[col] : 0.0f;
            #pragma unroll
            for (int r = 0; r < 4; ++r) {
                size_t off = (size_t)(r0 + r) * ldc + col;
                float v = acc[i][j][r] + bb;
                if constexpr (sizeof(TC) == 2) {
                    C[off] = f2bf(v);
                } else {
                    if (EPI == 2) v += C[off];
                    C[off] = v;
                }
            }
        }
    }
}

// ---------------- Small-N direct MFMA GEMM: C(M,N) = A(M,K) @ W(N,K)^T ----------------
// W fp32, converted in-register. Wave tile 16 x (NF*16); block = 64 rows.
// EPI: 0 none, 1 +bias, 2 softplus(+bias).
template<int NF, typename TA, typename TC, int EPI>
__global__ __launch_bounds__(256) void gemm_smalln_kernel(
    const TA* __restrict__ A, int lda,
    const float* __restrict__ W, int ldw,
    const float* __restrict__ bias,
    TC* __restrict__ C, int ldc, int K)
{
    const int tid  = threadIdx.x;
    const int wv   = tid >> 6;
    const int lane = tid & 63;
    const int l15  = lane & 15;
    const int kq   = lane >> 4;
    const int row  = blockIdx.y * 64 + wv * 16 + l15;
    const int bn   = blockIdx.x * (NF * 16);
    const bf16x8 zero8 = {0,0,0,0,0,0,0,0};

    f32x4 acc[NF];
    #pragma unroll
    for (int j = 0; j < NF; ++j) acc[j] = (f32x4){0.f, 0.f, 0.f, 0.f};

    for (int k0 = 0; k0 < K; k0 += 32) {
        int kk = k0 + kq * 8;
        bool kv = kk < K;
        int ko = kv ? kk : 0;
        bf16x8 a;
        if constexpr (sizeof(TA) == 2) {
            a = *(const bf16x8*)(A + (size_t)row * lda + ko);
        } else {
            const float* ap = A + (size_t)row * lda + ko;
            a = pack8(*(const float4*)ap, *(const float4*)(ap + 4));
        }
        if (!kv) a = zero8;
        bf16x8 b[NF];
        #pragma unroll
        for (int j = 0; j < NF; ++j) {
            int n = bn + j * 16 + l15;
            const float* wp = W + (size_t)n * ldw + ko;
            b[j] = pack8(*(const float4*)wp, *(const float4*)(wp + 4));
            if (!kv) b[j] = zero8;
        }
        #pragma unroll
        for (int j = 0; j < NF; ++j)
            acc[j] = __builtin_amdgcn_mfma_f32_16x16x32_bf16(a, b[j], acc[j], 0, 0, 0);
    }

    const int r0 = blockIdx.y * 64 + wv * 16 + kq * 4;
    #pragma unroll
    for (int j = 0; j < NF; ++j) {
        int col = bn + j * 16 + l15;
        float bb = bias ? bias[col] : 0.0f;
        #pragma unroll
        for (int r = 0; r < 4; ++r) {
            float v = acc[j][r] + bb;
            if (EPI == 2) { float ax = fabsf(v); v = fmaxf(v, 0.f) + log1pf(__expf(-ax)); }
            size_t off = (size_t)(r0 + r) * ldc + col;
            if constexpr (sizeof(TC) == 2) C[off] = f2bf(v);
            else                           C[off] = v;
        }
    }
}

// ---------------- Causal depthwise conv (D_CONV=4) + SiLU: XZ u-half -> U ----------------
__global__ __launch_bounds__(256) void conv_silu_kernel(
    const bf16_t* __restrict__ xz, const float* __restrict__ cw,
    const float* __restrict__ cb, bf16_t* __restrict__ U)
{
    int idx = blockIdx.x * 256 + threadIdx.x;
    int d = idx % DI;
    int t = idx / DI;
    int s = t & (SEQ - 1);
    const bf16_t* base = xz + (size_t)t * (2*DI) + d;
    const float4 w = *(const float4*)(cw + d * 4);
    float acc = cb[d] + w.w * bf2f(base[0]);
    if (s >= 1) acc += w.z * bf2f(base[-(2*DI)]);
    if (s >= 2) acc += w.y * bf2f(base[-2*(2*DI)]);
    if (s >= 3) acc += w.x * bf2f(base[-3*(2*DI)]);
    U[(size_t)t * DI + d] = f2bf(acc * fast_sigmoid(acc));
}

// ---------------- Scan pass 1: per-chunk local scan -> HST (local end state), DTS ----------
// dt is read from the u-half of XZ (stride 2*DI).
__global__ __launch_bounds__(256) void scan1_kernel(
    const bf16_t* __restrict__ U, const bf16_t* __restrict__ XZ,
    const float* __restrict__ XDBL, const float* __restrict__ A_log,
    float* __restrict__ HST, float* __restrict__ DTS)
{
    const int d = blockIdx.x * 256 + threadIdx.x;
    const int c = blockIdx.y;
    const int b = blockIdx.z;
    float Arow[DST];
    #pragma unroll
    for (int n = 0; n < DST; ++n) Arow[n] = -__expf(A_log[(size_t)d * DST + n]);
    float h[DST];
    #pragma unroll
    for (int n = 0; n < DST; ++n) h[n] = 0.f;
    float dtsum = 0.f;
    __shared__ __align__(16) float bs[CHK][DST];
    const size_t tbase = (size_t)b * SEQ + (size_t)c * CHK;
    for (int q = threadIdx.x; q < CHK * 4; q += 256) {
        int tt = q >> 2, j = q & 3;
        ((float4*)bs[tt])[j] = *(const float4*)(XDBL + (tbase + tt) * NXP + DTR + j * 4);
    }
    __syncthreads();
    for (int tt = 0; tt < CHK; ++tt) {
        size_t t = tbase + tt;
        float ut  = bf2f(U[t * DI + d]);
        float dtt = bf2f(XZ[t * (2*DI) + d]);
        dtsum += dtt;
        float du = dtt * ut;
        const float* bp = bs[tt];
        float4 b0 = *(const float4*)(bp);
        float4 b1 = *(const float4*)(bp + 4);
        float4 b2 = *(const float4*)(bp + 8);
        float4 b3 = *(const float4*)(bp + 12);
        float bv[16] = {b0.x,b0.y,b0.z,b0.w, b1.x,b1.y,b1.z,b1.w,
                        b2.x,b2.y,b2.z,b2.w, b3.x,b3.y,b3.z,b3.w};
        #pragma unroll
        for (int n = 0; n < DST; ++n) {
            float dA = __expf(dtt * Arow[n]);
            h[n] = h[n] * dA + du * bv[n];
        }
    }
    size_t base = (((size_t)b * NCHK + c) * DI + d) * DST;
    #pragma unroll
    for (int n = 0; n < DST; ++n) HST[base + n] = h[n];
    DTS[((size_t)b * NCHK + c) * DI + d] = dtsum;
}

// ---------------- Scan pass 2: inter-chunk scan; HST -> incoming state ----------
__global__ __launch_bounds__(256) void scan2_kernel(
    const float* __restrict__ A_log, const float* __restrict__ DTS,
    float* __restrict__ HST)
{
    int gid = blockIdx.x * 256 + threadIdx.x;    // over BATCHN*DI*DST
    int n = gid & 15;
    int rem = gid >> 4;
    int d = rem % DI;
    int b = rem / DI;
    float An = -__expf(A_log[(size_t)d * DST + n]);
    float h = 0.f;
    for (int c = 0; c < NCHK; ++c) {
        size_t sidx = (((size_t)b * NCHK + c) * DI + d) * DST + n;
        float localend = HST[sidx];
        float a = __expf(An * DTS[((size_t)b * NCHK + c) * DI + d]);
        HST[sidx] = h;
        h = a * h + localend;
    }
}

// ---------------- Scan pass 3: local scan + y + Dskip + z-gate; y -> XZ u-half ----------
// dt read from XZ u-half, z from XZ z-half; gated y overwrites the dt slot (same thread,
// read-before-write).
__global__ __launch_bounds__(256) void scan3_kernel(
    const bf16_t* __restrict__ U, const float* __restrict__ XDBL,
    const float* __restrict__ A_log, const float* __restrict__ Dp,
    const float* __restrict__ HST, bf16_t* __restrict__ XZ)
{
    const int d = blockIdx.x * 256 + threadIdx.x;
    const int c = blockIdx.y;
    const int b = blockIdx.z;
    float Arow[DST];
    #pragma unroll
    for (int n = 0; n < DST; ++n) Arow[n] = -__expf(A_log[(size_t)d * DST + n]);
    const float dp = Dp[d];
    float h[DST];
    size_t base = (((size_t)b * NCHK + c) * DI + d) * DST;
    #pragma unroll
    for (int n = 0; n < DST; ++n) h[n] = HST[base + n];
    __shared__ __align__(16) float bc[CHK][2 * DST];
    const size_t tbase = (size_t)b * SEQ + (size_t)c * CHK;
    for (int q = threadIdx.x; q < CHK * 8; q += 256) {
        int tt = q >> 3, j = q & 7;
        ((float4*)bc[tt])[j] = *(const float4*)(XDBL + (tbase + tt) * NXP + DTR + j * 4);
    }
    __syncthreads();
    for (int tt = 0; tt < CHK; ++tt) {
        size_t t = tbase + tt;
        float ut  = bf2f(U[t * DI + d]);
        float dtt = bf2f(XZ[t * (2*DI) + d]);
        float du = dtt * ut;
        const float* bp = bc[tt];
        float4 b0 = *(const float4*)(bp);
        float4 b1 = *(const float4*)(bp + 4);
        float4 b2 = *(const float4*)(bp + 8);
        float4 b3 = *(const float4*)(bp + 12);
        float4 c0 = *(const float4*)(bp + 16);
        float4 c1 = *(const float4*)(bp + 20);
        float4 c2 = *(const float4*)(bp + 24);
        float4 c3 = *(const float4*)(bp + 28);
        float bv[16] = {b0.x,b0.y,b0.z,b0.w, b1.x,b1.y,b1.z,b1.w,
                        b2.x,b2.y,b2.z,b2.w, b3.x,b3.y,b3.z,b3.w};
        float cv[16] = {c0.x,c0.y,c0.z,c0.w, c1.x,c1.y,c1.z,c1.w,
                        c2.x,c2.y,c2.z,c2.w, c3.x,c3.y,c3.z,c3.w};
        float y = 0.f;
        #pragma unroll
        for (int n = 0; n < DST; ++n) {
            float dA = __expf(dtt * Arow[n]);
            h[n] = h[n] * dA + du * bv[n];
            y += h[n] * cv[n];
        }
        y += ut * dp;
        float z = bf2f(XZ[t * (2*DI) + DI + d]);
        XZ[t * (2*DI) + d] = f2bf(y * z * fast_sigmoid(z));
    }
}

extern "C" void kernel_launch(void* const* d_in, const int* in_sizes, int n_in,
                              void* d_out, int out_size, void* d_ws, size_t ws_size,
                              hipStream_t stream) {
    const float* obs       = (const float*)d_in[0];
    const float* in_norm_g = (const float*)d_in[1];
    const float* in_norm_b = (const float*)d_in[2];
    const float* in_W      = (const float*)d_in[3];
    const float* in_b      = (const float*)d_in[4];
    const float* norm_g    = (const float*)d_in[5];
    const float* norm_b    = (const float*)d_in[6];
    const float* inproj_W  = (const float*)d_in[7];
    const float* conv_W    = (const float*)d_in[8];
    const float* conv_b    = (const float*)d_in[9];
    const float* xproj_W   = (const float*)d_in[10];
    const float* dt_W      = (const float*)d_in[11];
    const float* dt_b      = (const float*)d_in[12];
    const float* A_log     = (const float*)d_in[13];
    const float* D_param   = (const float*)d_in[14];
    const float* outproj_W = (const float*)d_in[15];
    const float* out_W     = (const float*)d_in[16];
    const float* out_b     = (const float*)d_in[17];
    float* out = (float*)d_out;

    // Workspace (~226 MB): X | XDBL | XZ | U | WBUF | HST | DTS
    //   XZ (BS x 2*DI bf16): [u_raw | z] per row; dt overwrites u_raw slot; gated y
    //   overwrites dt slot in scan3.
    float*  X    = (float*)d_ws;
    float*  XDBL = X + (size_t)BS * DM;
    bf16_t* XZ   = (bf16_t*)(XDBL + (size_t)BS * NXP);
    bf16_t* U    = XZ + (size_t)BS * 2 * DI;
    bf16_t* WBUF = U + (size_t)BS * DI;
    float*  HST  = (float*)(WBUF + (size_t)3538944);
    float*  DTS  = HST + (size_t)BATCHN * NCHK * DI * DST;
    bf16_t* OBSN = XZ;          // live only before layer loop
    bf16_t* XN   = U;           // live only between ln and inproj GEMM
    bf16_t* WB_ip = WBUF;                          // 2*DI*DM
    bf16_t* WB_op = WBUF + (size_t)2 * DI * DM;    // DM*DI

    // 1) input layernorm + in projection (small-N MFMA, fp32 W direct)
    ln_kernel<bf16_t><<<BS, 256, 0, stream>>>(obs, in_norm_g, in_norm_b, OBSN, OBSD);
    gemm_smalln_kernel<4, bf16_t, float, 1><<<dim3(DM/64, BS/64), 256, 0, stream>>>(
        OBSN, OBSD, in_W, OBSD, in_b, X, DM, OBSD);

    for (int l = 0; l < 2; ++l) {
        const float* ipW = inproj_W  + (size_t)l * (2*DI) * DM;
        const float* cW  = conv_W    + (size_t)l * DI * 4;
        const float* cB  = conv_b    + (size_t)l * DI;
        const float* xpW = xproj_W   + (size_t)l * NXP * DI;
        const float* dW  = dt_W      + (size_t)l * DI * DTR;
        const float* dB  = dt_b      + (size_t)l * DI;
        const float* Al  = A_log     + (size_t)l * DI * DST;
        const float* Dpl = D_param   + (size_t)l * DI;
        const float* opW = outproj_W + (size_t)l * DM * DI;

        cvt_f2bf_kernel<<<(2*DI*DM/4 + 255)/256, 256, 0, stream>>>(ipW, WB_ip, 2*DI*DM/4);
        cvt_f2bf_kernel<<<(DM*DI/4 + 255)/256, 256, 0, stream>>>(opW, WB_op, DM*DI/4);

        ln_kernel<bf16_t><<<BS, 256, 0, stream>>>(X, norm_g + l*DM, norm_b + l*DM, XN, DM);
        // xz = xn @ ipW.T  (merged u|z, N = 3072, interleaved rows)
        gemm_lds_kernel<bf16_t, 0><<<dim3((2*DI)/128, BS/128), 256, 0, stream>>>(
            XN, DM, WB_ip, DM, nullptr, XZ, 2*DI, DM);
        // u = silu(conv(u_raw))
        conv_silu_kernel<<<(BS*DI)/256, 256, 0, stream>>>(XZ, cW, cB, U);
        // x_dbl = u @ xpW.T  (N = 80 exact: NF=5)
        gemm_smalln_kernel<5, bf16_t, float, 0><<<dim3(1, BS/64), 256, 0, stream>>>(
            U, DI, xpW, DI, nullptr, XDBL, NXP, DI);
        // dt = softplus(x_dbl[:, :48] @ dtW.T + dt_b) -> XZ u-half (u_raw dead)
        gemm_smalln_kernel<4, float, bf16_t, 2><<<dim3(DI/64, BS/64), 256, 0, stream>>>(
            XDBL, NXP, dW, DTR, dB, XZ, 2*DI, DTR);
        // three-pass chunked selective scan
        scan1_kernel<<<dim3(DI/256, NCHK, BATCHN), 256, 0, stream>>>(
            U, XZ, XDBL, Al, HST, DTS);
        scan2_kernel<<<(BATCHN*DI*DST)/256, 256, 0, stream>>>(Al, DTS, HST);
        scan3_kernel<<<dim3(DI/256, NCHK, BATCHN), 256, 0, stream>>>(
            U, XDBL, Al, Dpl, HST, XZ);
        // x += y @ opW.T (LDS-staged MFMA, accumulate into fp32 X; y in XZ u-half, lda 2*DI)
        gemm_lds_kernel<float, 2><<<dim3(DM/128, BS/128), 256, 0, stream>>>(
            XZ, 2*DI, WB_op, DI, nullptr, X, DM, DI);
    }

    // out = x @ out_W.T + out_b  (N = 64 exact: NF=4)
    gemm_smalln_kernel<4, float, float, 1><<<dim3(1, BS/64), 256, 0, stream>>>(
        X, DM, out_W, DM, out_b, out, 64, DM);
}